// Round 1
// baseline (2998.607 us; speedup 1.0000x reference)
//
#include <hip/hip_runtime.h>
#include <hip/hip_bf16.h>
#include <math.h>

// ---------------- model constants ----------------
#define NNODES 10000
#define NEDGES 160000
#define NB     256
#define ETOT   (NEDGES + NNODES)   // with self loops
#define INDIM  57
#define DESCD  1217

// GAT layer dims (in, H, C)
// L1: 57  -> 5x114 (570)
// L2: 570 -> 5x171 (855)
// L3: 855 -> 5x114 (570)
// L4: 570 -> 1x570 (570)

static inline size_t align256(size_t x) { return (x + 255) & ~size_t(255); }

// ---------------- wave helpers ----------------
__device__ inline float wave_max(float v) {
#pragma unroll
  for (int o = 32; o > 0; o >>= 1) v = fmaxf(v, __shfl_xor(v, o));
  return v;
}
__device__ inline float wave_sum(float v) {
#pragma unroll
  for (int o = 32; o > 0; o >>= 1) v += __shfl_xor(v, o);
  return v;
}

// ---------------- CSR build ----------------
__global__ void count_kernel(const int* __restrict__ ei, int* __restrict__ deg) {
  int e = blockIdx.x * blockDim.x + threadIdx.x;
  if (e < ETOT) {
    int dst = (e < NEDGES) ? ei[NEDGES + e] : (e - NEDGES);
    atomicAdd(&deg[dst], 1);
  }
}

__global__ __launch_bounds__(1024) void scan_kernel(const int* __restrict__ deg,
                                                    int* __restrict__ row_ptr,
                                                    int* __restrict__ cursor) {
  __shared__ int part[1024];
  const int CHUNK = (NNODES + 1023) / 1024;  // 10
  int t = threadIdx.x;
  int start = t * CHUNK;
  int sum = 0;
  for (int i = 0; i < CHUNK; ++i) {
    int idx = start + i;
    if (idx < NNODES) sum += deg[idx];
  }
  part[t] = sum;
  __syncthreads();
  // Hillis-Steele inclusive scan
  for (int off = 1; off < 1024; off <<= 1) {
    int v = (t >= off) ? part[t - off] : 0;
    __syncthreads();
    part[t] += v;
    __syncthreads();
  }
  int run = (t > 0) ? part[t - 1] : 0;
  for (int i = 0; i < CHUNK; ++i) {
    int idx = start + i;
    if (idx < NNODES) {
      row_ptr[idx] = run;
      cursor[idx] = run;
      run += deg[idx];
    }
  }
  if (t == 1023) row_ptr[NNODES] = ETOT;
}

__global__ void scatter_kernel(const int* __restrict__ ei, int* __restrict__ cursor,
                               int* __restrict__ csr_src) {
  int e = blockIdx.x * blockDim.x + threadIdx.x;
  if (e < ETOT) {
    int src, dst;
    if (e < NEDGES) { src = ei[e]; dst = ei[NEDGES + e]; }
    else            { src = e - NEDGES; dst = src; }
    int idx = atomicAdd(&cursor[dst], 1);
    csr_src[idx] = src;
  }
}

// ---------------- generic fp32 GEMM: C = A[M,K] @ W[K,N] (+bias) (opt relu) ----------------
__global__ __launch_bounds__(256) void gemm_kernel(const float* __restrict__ A,
                                                   const float* __restrict__ W,
                                                   const float* __restrict__ bias,
                                                   float* __restrict__ Cm,
                                                   int M, int K, int N, int relu) {
  __shared__ float As[16][65];
  __shared__ float Bs[16][65];
  int tid = threadIdx.x;
  int tx = tid % 16, ty = tid / 16;
  int m0 = blockIdx.y * 64, n0 = blockIdx.x * 64;
  float acc[4][4] = {};
  for (int k0 = 0; k0 < K; k0 += 16) {
    {
      int c = tid % 16;
      int r = tid / 16;
#pragma unroll
      for (int i = 0; i < 4; ++i) {
        int rr = r + i * 16;
        int gm = m0 + rr, gk = k0 + c;
        As[c][rr] = (gm < M && gk < K) ? A[(size_t)gm * K + gk] : 0.f;
      }
      int nn = tid % 64;
      int kk = tid / 64;
#pragma unroll
      for (int i = 0; i < 4; ++i) {
        int kkk = kk + i * 4;
        int gk = k0 + kkk, gn = n0 + nn;
        Bs[kkk][nn] = (gk < K && gn < N) ? W[(size_t)gk * N + gn] : 0.f;
      }
    }
    __syncthreads();
#pragma unroll
    for (int kk = 0; kk < 16; ++kk) {
      float a[4], b[4];
#pragma unroll
      for (int i = 0; i < 4; ++i) a[i] = As[kk][ty * 4 + i];
#pragma unroll
      for (int j = 0; j < 4; ++j) b[j] = Bs[kk][tx * 4 + j];
#pragma unroll
      for (int i = 0; i < 4; ++i)
#pragma unroll
        for (int j = 0; j < 4; ++j) acc[i][j] += a[i] * b[j];
    }
    __syncthreads();
  }
#pragma unroll
  for (int i = 0; i < 4; ++i) {
    int gm = m0 + ty * 4 + i;
    if (gm >= M) continue;
#pragma unroll
    for (int j = 0; j < 4; ++j) {
      int gn = n0 + tx * 4 + j;
      if (gn >= N) continue;
      float v = acc[i][j] + (bias ? bias[gn] : 0.f);
      if (relu) v = fmaxf(v, 0.f);
      Cm[(size_t)gm * N + gn] = v;
    }
  }
}

// ---------------- attention logit dots: als/ald [N,H] ----------------
__global__ __launch_bounds__(256) void al_kernel(const float* __restrict__ hbuf,
                                                 const float* __restrict__ a_s,
                                                 const float* __restrict__ a_d,
                                                 float* __restrict__ als,
                                                 float* __restrict__ ald,
                                                 int H, int C) {
  int wid = threadIdx.x >> 6, lane = threadIdx.x & 63;
  int g = blockIdx.x * 4 + wid;
  if (g >= NNODES * H) return;
  int n = g / H, h = g % H;
  const float* hr = hbuf + (size_t)n * H * C + (size_t)h * C;
  float ss = 0.f, sd = 0.f;
  for (int c = lane; c < C; c += 64) {
    float v = hr[c];
    ss += v * a_s[h * C + c];
    sd += v * a_d[h * C + c];
  }
  ss = wave_sum(ss);
  sd = wave_sum(sd);
  if (lane == 0) { als[g] = ss; ald[g] = sd; }
}

// ---------------- per-node segment softmax -> alpha per CSR slot ----------------
__global__ __launch_bounds__(256) void att_kernel(const float* __restrict__ als,
                                                  const float* __restrict__ ald,
                                                  const int* __restrict__ row_ptr,
                                                  const int* __restrict__ csr_src,
                                                  float* __restrict__ alpha, int H) {
  int wid = threadIdx.x >> 6, lane = threadIdx.x & 63;
  int n = blockIdx.x * 4 + wid;
  if (n >= NNODES) return;
  int rp = row_ptr[n], deg = row_ptr[n + 1] - rp;
  for (int h = 0; h < H; ++h) {
    float ad = ald[n * H + h];
    float m = -1e30f;
    for (int j = lane; j < deg; j += 64) {
      int s = csr_src[rp + j];
      float e = als[s * H + h] + ad;
      e = (e >= 0.f) ? e : 0.2f * e;
      m = fmaxf(m, e);
    }
    m = wave_max(m);
    float ssum = 0.f;
    for (int j = lane; j < deg; j += 64) {
      int s = csr_src[rp + j];
      float e = als[s * H + h] + ad;
      e = (e >= 0.f) ? e : 0.2f * e;
      ssum += expf(e - m);
    }
    ssum = wave_sum(ssum);
    float inv = 1.f / (ssum + 1e-16f);
    for (int j = lane; j < deg; j += 64) {
      int s = csr_src[rp + j];
      float e = als[s * H + h] + ad;
      e = (e >= 0.f) ? e : 0.2f * e;
      alpha[(size_t)(rp + j) * H + h] = expf(e - m) * inv;
    }
  }
}

// ---------------- message aggregation + bias + relu ----------------
__global__ __launch_bounds__(256) void agg_kernel(const float* __restrict__ hbuf,
                                                  const float* __restrict__ alpha,
                                                  const int* __restrict__ row_ptr,
                                                  const int* __restrict__ csr_src,
                                                  const float* __restrict__ bias,
                                                  float* __restrict__ out, int H, int C) {
  int wid = threadIdx.x >> 6, lane = threadIdx.x & 63;
  int n = blockIdx.x * 4 + wid;
  if (n >= NNODES) return;
  int rp = row_ptr[n], deg = row_ptr[n + 1] - rp;
  int HC = H * C;
  for (int k = lane; k < HC; k += 64) {
    int head = k / C;
    float acc = bias[k];
    for (int j = 0; j < deg; ++j) {
      int s = csr_src[rp + j];
      float a = alpha[(size_t)(rp + j) * H + head];
      acc += a * hbuf[(size_t)s * HC + k];
    }
    out[(size_t)n * HC + k] = fmaxf(acc, 0.f);  // relu after every GAT layer
  }
}

// ---------------- global add pool ----------------
__global__ __launch_bounds__(256) void pool_kernel(const float* __restrict__ h4,
                                                   const int* __restrict__ batch,
                                                   float* __restrict__ pooled, int F) {
  int wid = threadIdx.x >> 6, lane = threadIdx.x & 63;
  int n = blockIdx.x * 4 + wid;
  if (n >= NNODES) return;
  int b = batch[n];
  for (int k = lane; k < F; k += 64) atomicAdd(&pooled[(size_t)b * F + k], h4[(size_t)n * F + k]);
}

// ---------------- concat [g | desc] ----------------
__global__ void concat_kernel(const float* __restrict__ g, const float* __restrict__ desc,
                              float* __restrict__ z) {
  const int W = 1024 + DESCD;
  int idx = blockIdx.x * blockDim.x + threadIdx.x;
  if (idx < NB * W) {
    int b = idx / W, c = idx % W;
    z[idx] = (c < 1024) ? g[b * 1024 + c] : desc[b * DESCD + (c - 1024)];
  }
}

// ---------------- launch ----------------
extern "C" void kernel_launch(void* const* d_in, const int* in_sizes, int n_in,
                              void* d_out, int out_size, void* d_ws, size_t ws_size,
                              hipStream_t stream) {
  const float* x    = (const float*)d_in[0];
  const int*   ei   = (const int*)d_in[1];
  const int*   batch= (const int*)d_in[2];
  const float* desc = (const float*)d_in[3];
  const float* W1 = (const float*)d_in[4];  const float* as1 = (const float*)d_in[5];
  const float* ad1 = (const float*)d_in[6]; const float* b1 = (const float*)d_in[7];
  const float* W2 = (const float*)d_in[8];  const float* as2 = (const float*)d_in[9];
  const float* ad2 = (const float*)d_in[10];const float* b2 = (const float*)d_in[11];
  const float* W3 = (const float*)d_in[12]; const float* as3 = (const float*)d_in[13];
  const float* ad3 = (const float*)d_in[14];const float* b3 = (const float*)d_in[15];
  const float* W4 = (const float*)d_in[16]; const float* as4 = (const float*)d_in[17];
  const float* ad4 = (const float*)d_in[18];const float* b4 = (const float*)d_in[19];
  const float* Wg = (const float*)d_in[20]; const float* bg = (const float*)d_in[21];
  const float* Wf1 = (const float*)d_in[22];const float* bf1 = (const float*)d_in[23];
  const float* Wf2 = (const float*)d_in[24];const float* bf2 = (const float*)d_in[25];
  const float* Wf3 = (const float*)d_in[26];const float* bf3 = (const float*)d_in[27];
  const float* Wf4 = (const float*)d_in[28];const float* bf4 = (const float*)d_in[29];
  const float* Wf5 = (const float*)d_in[30];const float* bf5 = (const float*)d_in[31];
  float* out = (float*)d_out;

  // ---- workspace carve-up ----
  char* p = (char*)d_ws;
  size_t off = 0;
  auto alloc = [&](size_t bytes) -> char* {
    char* r = p + off;
    off = align256(off + bytes);
    return r;
  };
  int*   deg     = (int*)alloc(sizeof(int) * NNODES);
  int*   row_ptr = (int*)alloc(sizeof(int) * (NNODES + 1));
  int*   cursor  = (int*)alloc(sizeof(int) * NNODES);
  int*   csr_src = (int*)alloc(sizeof(int) * ETOT);
  float* als     = (float*)alloc(sizeof(float) * NNODES * 5);
  float* ald     = (float*)alloc(sizeof(float) * NNODES * 5);
  float* alpha   = (float*)alloc(sizeof(float) * (size_t)ETOT * 5);
  float* hA      = (float*)alloc(sizeof(float) * (size_t)NNODES * 855);
  float* hB      = (float*)alloc(sizeof(float) * (size_t)NNODES * 855);
  float* pooled  = (float*)alloc(sizeof(float) * NB * 570);
  float* gbuf    = (float*)alloc(sizeof(float) * NB * 1024);
  float* zbuf    = (float*)alloc(sizeof(float) * NB * (1024 + DESCD));
  float* t1      = (float*)alloc(sizeof(float) * NB * 2048);
  float* t2      = (float*)alloc(sizeof(float) * NB * 2048);
  (void)ws_size;

  // ---- CSR build ----
  hipMemsetAsync(deg, 0, sizeof(int) * NNODES, stream);
  {
    dim3 g((ETOT + 255) / 256);
    count_kernel<<<g, 256, 0, stream>>>(ei, deg);
    scan_kernel<<<1, 1024, 0, stream>>>(deg, row_ptr, cursor);
    scatter_kernel<<<g, 256, 0, stream>>>(ei, cursor, csr_src);
  }

  dim3 gnode((NNODES + 3) / 4);

  // ---- GAT layers ----
  struct LayerDef { const float* in; const float* W; const float* a_s; const float* a_d;
                    const float* b; int K; int H; int C; };
  LayerDef layers[4] = {
    { x,  W1, as1, ad1, b1, INDIM, 5, 114 },
    { hB, W2, as2, ad2, b2, 570,   5, 171 },
    { hB, W3, as3, ad3, b3, 855,   5, 114 },
    { hB, W4, as4, ad4, b4, 570,   1, 570 },
  };
  for (int l = 0; l < 4; ++l) {
    LayerDef& L = layers[l];
    int HC = L.H * L.C;
    // h = in @ W  -> hA
    {
      dim3 g((HC + 63) / 64, (NNODES + 63) / 64);
      gemm_kernel<<<g, 256, 0, stream>>>(L.in, L.W, nullptr, hA, NNODES, L.K, HC, 0);
    }
    // attention logits
    {
      dim3 g((NNODES * L.H + 3) / 4);
      al_kernel<<<g, 256, 0, stream>>>(hA, L.a_s, L.a_d, als, ald, L.H, L.C);
    }
    att_kernel<<<gnode, 256, 0, stream>>>(als, ald, row_ptr, csr_src, alpha, L.H);
    agg_kernel<<<gnode, 256, 0, stream>>>(hA, alpha, row_ptr, csr_src, L.b, hB, L.H, L.C);
  }

  // ---- pooling ----
  hipMemsetAsync(pooled, 0, sizeof(float) * NB * 570, stream);
  pool_kernel<<<gnode, 256, 0, stream>>>(hB, batch, pooled, 570);

  // ---- head MLP ----
  auto gemm = [&](const float* A, const float* W, const float* bias, float* C,
                  int M, int K, int N, int relu) {
    dim3 g((N + 63) / 64, (M + 63) / 64);
    gemm_kernel<<<g, 256, 0, stream>>>(A, W, bias, C, M, K, N, relu);
  };
  gemm(pooled, Wg, bg, gbuf, NB, 570, 1024, 0);
  {
    int tot = NB * (1024 + DESCD);
    concat_kernel<<<(tot + 255) / 256, 256, 0, stream>>>(gbuf, desc, zbuf);
  }
  gemm(zbuf, Wf1, bf1, t1, NB, 1024 + DESCD, 1024, 1);
  gemm(t1,   Wf2, bf2, t2, NB, 1024, 2048, 1);
  gemm(t2,   Wf3, bf3, t1, NB, 2048, 1024, 1);
  gemm(t1,   Wf4, bf4, t2, NB, 1024, 256, 1);
  gemm(t2,   Wf5, bf5, out, NB, 256, 1, 0);
}

// Round 2
// 1904.494 us; speedup vs baseline: 1.5745x; 1.5745x over previous
//
#include <hip/hip_runtime.h>
#include <hip/hip_bf16.h>
#include <math.h>

// ---------------- model constants ----------------
#define NNODES 10000
#define NEDGES 160000
#define NB     256
#define ETOT   (NEDGES + NNODES)   // with self loops
#define INDIM  57
#define DESCD  1217

static inline size_t align256(size_t x) { return (x + 255) & ~size_t(255); }

// ---------------- wave helpers ----------------
__device__ inline float wave_max(float v) {
#pragma unroll
  for (int o = 32; o > 0; o >>= 1) v = fmaxf(v, __shfl_xor(v, o));
  return v;
}
__device__ inline float wave_sum(float v) {
#pragma unroll
  for (int o = 32; o > 0; o >>= 1) v += __shfl_xor(v, o);
  return v;
}

// ---------------- CSR build ----------------
__global__ void count_kernel(const int* __restrict__ ei, int* __restrict__ deg) {
  int e = blockIdx.x * blockDim.x + threadIdx.x;
  if (e < ETOT) {
    int dst = (e < NEDGES) ? ei[NEDGES + e] : (e - NEDGES);
    atomicAdd(&deg[dst], 1);
  }
}

__global__ __launch_bounds__(1024) void scan_kernel(const int* __restrict__ deg,
                                                    int* __restrict__ row_ptr,
                                                    int* __restrict__ cursor) {
  __shared__ int part[1024];
  const int CHUNK = (NNODES + 1023) / 1024;  // 10
  int t = threadIdx.x;
  int start = t * CHUNK;
  int sum = 0;
  for (int i = 0; i < CHUNK; ++i) {
    int idx = start + i;
    if (idx < NNODES) sum += deg[idx];
  }
  part[t] = sum;
  __syncthreads();
  for (int off = 1; off < 1024; off <<= 1) {
    int v = (t >= off) ? part[t - off] : 0;
    __syncthreads();
    part[t] += v;
    __syncthreads();
  }
  int run = (t > 0) ? part[t - 1] : 0;
  for (int i = 0; i < CHUNK; ++i) {
    int idx = start + i;
    if (idx < NNODES) {
      row_ptr[idx] = run;
      cursor[idx] = run;
      run += deg[idx];
    }
  }
  if (t == 1023) row_ptr[NNODES] = ETOT;
}

__global__ void scatter_kernel(const int* __restrict__ ei, int* __restrict__ cursor,
                               int* __restrict__ csr_src) {
  int e = blockIdx.x * blockDim.x + threadIdx.x;
  if (e < ETOT) {
    int src, dst;
    if (e < NEDGES) { src = ei[e]; dst = ei[NEDGES + e]; }
    else            { src = e - NEDGES; dst = src; }
    int idx = atomicAdd(&cursor[dst], 1);
    csr_src[idx] = src;
  }
}

// ---------------- generic fp32 GEMM: C = A[M,K] @ W[K,N] (+bias) (opt relu) ----------------
__global__ __launch_bounds__(256) void gemm_kernel(const float* __restrict__ A,
                                                   const float* __restrict__ W,
                                                   const float* __restrict__ bias,
                                                   float* __restrict__ Cm,
                                                   int M, int K, int N, int relu) {
  __shared__ float As[16][65];
  __shared__ float Bs[16][65];
  int tid = threadIdx.x;
  int tx = tid % 16, ty = tid / 16;
  int m0 = blockIdx.y * 64, n0 = blockIdx.x * 64;
  float acc[4][4] = {};
  for (int k0 = 0; k0 < K; k0 += 16) {
    {
      int c = tid % 16;
      int r = tid / 16;
#pragma unroll
      for (int i = 0; i < 4; ++i) {
        int rr = r + i * 16;
        int gm = m0 + rr, gk = k0 + c;
        As[c][rr] = (gm < M && gk < K) ? A[(size_t)gm * K + gk] : 0.f;
      }
      int nn = tid % 64;
      int kk = tid / 64;
#pragma unroll
      for (int i = 0; i < 4; ++i) {
        int kkk = kk + i * 4;
        int gk = k0 + kkk, gn = n0 + nn;
        Bs[kkk][nn] = (gk < K && gn < N) ? W[(size_t)gk * N + gn] : 0.f;
      }
    }
    __syncthreads();
#pragma unroll
    for (int kk = 0; kk < 16; ++kk) {
      float a[4], b[4];
#pragma unroll
      for (int i = 0; i < 4; ++i) a[i] = As[kk][ty * 4 + i];
#pragma unroll
      for (int j = 0; j < 4; ++j) b[j] = Bs[kk][tx * 4 + j];
#pragma unroll
      for (int i = 0; i < 4; ++i)
#pragma unroll
        for (int j = 0; j < 4; ++j) acc[i][j] += a[i] * b[j];
    }
    __syncthreads();
  }
#pragma unroll
  for (int i = 0; i < 4; ++i) {
    int gm = m0 + ty * 4 + i;
    if (gm >= M) continue;
#pragma unroll
    for (int j = 0; j < 4; ++j) {
      int gn = n0 + tx * 4 + j;
      if (gn >= N) continue;
      float v = acc[i][j] + (bias ? bias[gn] : 0.f);
      if (relu) v = fmaxf(v, 0.f);
      Cm[(size_t)gm * N + gn] = v;
    }
  }
}

// ---------------- split-K fp32 GEMM: P[z] = A[M,Kc] @ W[Kc,N] partials ----------------
__global__ __launch_bounds__(256) void gemm_splitk_kernel(const float* __restrict__ A,
                                                          const float* __restrict__ W,
                                                          float* __restrict__ P,
                                                          int M, int K, int N, int kchunk) {
  __shared__ float As[16][65];
  __shared__ float Bs[16][65];
  int tid = threadIdx.x;
  int tx = tid % 16, ty = tid / 16;
  int m0 = blockIdx.y * 64, n0 = blockIdx.x * 64;
  int z = blockIdx.z;
  int kb = z * kchunk;
  int ke = min(K, kb + kchunk);
  float acc[4][4] = {};
  for (int k0 = kb; k0 < ke; k0 += 16) {
    {
      int c = tid % 16;
      int r = tid / 16;
#pragma unroll
      for (int i = 0; i < 4; ++i) {
        int rr = r + i * 16;
        int gm = m0 + rr, gk = k0 + c;
        As[c][rr] = (gm < M && gk < ke) ? A[(size_t)gm * K + gk] : 0.f;
      }
      int nn = tid % 64;
      int kk = tid / 64;
#pragma unroll
      for (int i = 0; i < 4; ++i) {
        int kkk = kk + i * 4;
        int gk = k0 + kkk, gn = n0 + nn;
        Bs[kkk][nn] = (gk < ke && gn < N) ? W[(size_t)gk * N + gn] : 0.f;
      }
    }
    __syncthreads();
#pragma unroll
    for (int kk = 0; kk < 16; ++kk) {
      float a[4], b[4];
#pragma unroll
      for (int i = 0; i < 4; ++i) a[i] = As[kk][ty * 4 + i];
#pragma unroll
      for (int j = 0; j < 4; ++j) b[j] = Bs[kk][tx * 4 + j];
#pragma unroll
      for (int i = 0; i < 4; ++i)
#pragma unroll
        for (int j = 0; j < 4; ++j) acc[i][j] += a[i] * b[j];
    }
    __syncthreads();
  }
  size_t base = (size_t)z * M * N;
#pragma unroll
  for (int i = 0; i < 4; ++i) {
    int gm = m0 + ty * 4 + i;
    if (gm >= M) continue;
#pragma unroll
    for (int j = 0; j < 4; ++j) {
      int gn = n0 + tx * 4 + j;
      if (gn >= N) continue;
      P[base + (size_t)gm * N + gn] = acc[i][j];
    }
  }
}

// ---------------- split-K reduce (+bias, opt relu) ----------------
__global__ void reduce_kernel(const float* __restrict__ P, const float* __restrict__ bias,
                              float* __restrict__ C, int MN, int N, int S, int relu) {
  int i = blockIdx.x * blockDim.x + threadIdx.x;
  if (i >= MN) return;
  float s = bias[i % N];
  for (int z = 0; z < S; ++z) s += P[(size_t)z * MN + i];
  C[i] = relu ? fmaxf(s, 0.f) : s;
}

// ---------------- FC5: [256,256] @ [256,1] wave-dot ----------------
__global__ __launch_bounds__(256) void fc5_kernel(const float* __restrict__ A,
                                                  const float* __restrict__ w,
                                                  const float* __restrict__ b,
                                                  float* __restrict__ out) {
  int wid = threadIdx.x >> 6, lane = threadIdx.x & 63;
  int m = blockIdx.x * 4 + wid;
  if (m >= NB) return;
  float s = 0.f;
  for (int k = lane; k < 256; k += 64) s += A[m * 256 + k] * w[k];
  s = wave_sum(s);
  if (lane == 0) out[m] = s + b[0];
}

// ---------------- attention logit dots: als/ald [N,H] ----------------
__global__ __launch_bounds__(256) void al_kernel(const float* __restrict__ hbuf,
                                                 const float* __restrict__ a_s,
                                                 const float* __restrict__ a_d,
                                                 float* __restrict__ als,
                                                 float* __restrict__ ald,
                                                 int H, int C) {
  int wid = threadIdx.x >> 6, lane = threadIdx.x & 63;
  int g = blockIdx.x * 4 + wid;
  if (g >= NNODES * H) return;
  int n = g / H, h = g % H;
  const float* hr = hbuf + (size_t)n * H * C + (size_t)h * C;
  float ss = 0.f, sd = 0.f;
  for (int c = lane; c < C; c += 64) {
    float v = hr[c];
    ss += v * a_s[h * C + c];
    sd += v * a_d[h * C + c];
  }
  ss = wave_sum(ss);
  sd = wave_sum(sd);
  if (lane == 0) { als[g] = ss; ald[g] = sd; }
}

// ---------------- per-node segment softmax -> alpha per CSR slot ----------------
__global__ __launch_bounds__(256) void att_kernel(const float* __restrict__ als,
                                                  const float* __restrict__ ald,
                                                  const int* __restrict__ row_ptr,
                                                  const int* __restrict__ csr_src,
                                                  float* __restrict__ alpha, int H) {
  int wid = threadIdx.x >> 6, lane = threadIdx.x & 63;
  int n = blockIdx.x * 4 + wid;
  if (n >= NNODES) return;
  int rp = row_ptr[n], deg = row_ptr[n + 1] - rp;
  for (int h = 0; h < H; ++h) {
    float ad = ald[n * H + h];
    float m = -1e30f;
    for (int j = lane; j < deg; j += 64) {
      int s = csr_src[rp + j];
      float e = als[s * H + h] + ad;
      e = (e >= 0.f) ? e : 0.2f * e;
      m = fmaxf(m, e);
    }
    m = wave_max(m);
    float ssum = 0.f;
    for (int j = lane; j < deg; j += 64) {
      int s = csr_src[rp + j];
      float e = als[s * H + h] + ad;
      e = (e >= 0.f) ? e : 0.2f * e;
      ssum += expf(e - m);
    }
    ssum = wave_sum(ssum);
    float inv = 1.f / (ssum + 1e-16f);
    for (int j = lane; j < deg; j += 64) {
      int s = csr_src[rp + j];
      float e = als[s * H + h] + ad;
      e = (e >= 0.f) ? e : 0.2f * e;
      alpha[(size_t)(rp + j) * H + h] = expf(e - m) * inv;
    }
  }
}

// ---------------- message aggregation + bias + relu ----------------
__global__ __launch_bounds__(256) void agg_kernel(const float* __restrict__ hbuf,
                                                  const float* __restrict__ alpha,
                                                  const int* __restrict__ row_ptr,
                                                  const int* __restrict__ csr_src,
                                                  const float* __restrict__ bias,
                                                  float* __restrict__ out, int H, int C) {
  int wid = threadIdx.x >> 6, lane = threadIdx.x & 63;
  int n = blockIdx.x * 4 + wid;
  if (n >= NNODES) return;
  int rp = row_ptr[n], deg = row_ptr[n + 1] - rp;
  int HC = H * C;
  for (int k = lane; k < HC; k += 64) {
    int head = k / C;
    float acc = bias[k];
    for (int j = 0; j < deg; ++j) {
      int s = csr_src[rp + j];
      float a = alpha[(size_t)(rp + j) * H + head];
      acc += a * hbuf[(size_t)s * HC + k];
    }
    out[(size_t)n * HC + k] = fmaxf(acc, 0.f);
  }
}

// ---------------- global add pool ----------------
__global__ __launch_bounds__(256) void pool_kernel(const float* __restrict__ h4,
                                                   const int* __restrict__ batch,
                                                   float* __restrict__ pooled, int F) {
  int wid = threadIdx.x >> 6, lane = threadIdx.x & 63;
  int n = blockIdx.x * 4 + wid;
  if (n >= NNODES) return;
  int b = batch[n];
  for (int k = lane; k < F; k += 64) atomicAdd(&pooled[(size_t)b * F + k], h4[(size_t)n * F + k]);
}

// ---------------- concat [g | desc] ----------------
__global__ void concat_kernel(const float* __restrict__ g, const float* __restrict__ desc,
                              float* __restrict__ z) {
  const int W = 1024 + DESCD;
  int idx = blockIdx.x * blockDim.x + threadIdx.x;
  if (idx < NB * W) {
    int b = idx / W, c = idx % W;
    z[idx] = (c < 1024) ? g[b * 1024 + c] : desc[b * DESCD + (c - 1024)];
  }
}

// ---------------- launch ----------------
extern "C" void kernel_launch(void* const* d_in, const int* in_sizes, int n_in,
                              void* d_out, int out_size, void* d_ws, size_t ws_size,
                              hipStream_t stream) {
  const float* x    = (const float*)d_in[0];
  const int*   ei   = (const int*)d_in[1];
  const int*   batch= (const int*)d_in[2];
  const float* desc = (const float*)d_in[3];
  const float* W1 = (const float*)d_in[4];  const float* as1 = (const float*)d_in[5];
  const float* ad1 = (const float*)d_in[6]; const float* b1 = (const float*)d_in[7];
  const float* W2 = (const float*)d_in[8];  const float* as2 = (const float*)d_in[9];
  const float* ad2 = (const float*)d_in[10];const float* b2 = (const float*)d_in[11];
  const float* W3 = (const float*)d_in[12]; const float* as3 = (const float*)d_in[13];
  const float* ad3 = (const float*)d_in[14];const float* b3 = (const float*)d_in[15];
  const float* W4 = (const float*)d_in[16]; const float* as4 = (const float*)d_in[17];
  const float* ad4 = (const float*)d_in[18];const float* b4 = (const float*)d_in[19];
  const float* Wg = (const float*)d_in[20]; const float* bg = (const float*)d_in[21];
  const float* Wf1 = (const float*)d_in[22];const float* bf1 = (const float*)d_in[23];
  const float* Wf2 = (const float*)d_in[24];const float* bf2 = (const float*)d_in[25];
  const float* Wf3 = (const float*)d_in[26];const float* bf3 = (const float*)d_in[27];
  const float* Wf4 = (const float*)d_in[28];const float* bf4 = (const float*)d_in[29];
  const float* Wf5 = (const float*)d_in[30];const float* bf5 = (const float*)d_in[31];
  float* out = (float*)d_out;

  // ---- workspace carve-up ----
  char* p = (char*)d_ws;
  size_t off = 0;
  auto alloc = [&](size_t bytes) -> char* {
    char* r = p + off;
    off = align256(off + bytes);
    return r;
  };
  int*   deg     = (int*)alloc(sizeof(int) * NNODES);
  int*   row_ptr = (int*)alloc(sizeof(int) * (NNODES + 1));
  int*   cursor  = (int*)alloc(sizeof(int) * NNODES);
  int*   csr_src = (int*)alloc(sizeof(int) * ETOT);
  float* als     = (float*)alloc(sizeof(float) * NNODES * 5);
  float* ald     = (float*)alloc(sizeof(float) * NNODES * 5);
  float* alpha   = (float*)alloc(sizeof(float) * (size_t)ETOT * 5);
  float* hA      = (float*)alloc(sizeof(float) * (size_t)NNODES * 855);  // also split-K partials after node phase
  float* hB      = (float*)alloc(sizeof(float) * (size_t)NNODES * 855);
  float* pooled  = (float*)alloc(sizeof(float) * NB * 570);
  float* gbuf    = (float*)alloc(sizeof(float) * NB * 1024);
  float* zbuf    = (float*)alloc(sizeof(float) * NB * (1024 + DESCD));
  float* t1      = (float*)alloc(sizeof(float) * NB * 2048);
  float* t2      = (float*)alloc(sizeof(float) * NB * 2048);
  (void)ws_size;

  // ---- CSR build ----
  hipMemsetAsync(deg, 0, sizeof(int) * NNODES, stream);
  {
    dim3 g((ETOT + 255) / 256);
    count_kernel<<<g, 256, 0, stream>>>(ei, deg);
    scan_kernel<<<1, 1024, 0, stream>>>(deg, row_ptr, cursor);
    scatter_kernel<<<g, 256, 0, stream>>>(ei, cursor, csr_src);
  }

  dim3 gnode((NNODES + 3) / 4);

  // ---- GAT layers ----
  struct LayerDef { const float* in; const float* W; const float* a_s; const float* a_d;
                    const float* b; int K; int H; int C; };
  LayerDef layers[4] = {
    { x,  W1, as1, ad1, b1, INDIM, 5, 114 },
    { hB, W2, as2, ad2, b2, 570,   5, 171 },
    { hB, W3, as3, ad3, b3, 855,   5, 114 },
    { hB, W4, as4, ad4, b4, 570,   1, 570 },
  };
  for (int l = 0; l < 4; ++l) {
    LayerDef& L = layers[l];
    int HC = L.H * L.C;
    {
      dim3 g((HC + 63) / 64, (NNODES + 63) / 64);
      gemm_kernel<<<g, 256, 0, stream>>>(L.in, L.W, nullptr, hA, NNODES, L.K, HC, 0);
    }
    {
      dim3 g((NNODES * L.H + 3) / 4);
      al_kernel<<<g, 256, 0, stream>>>(hA, L.a_s, L.a_d, als, ald, L.H, L.C);
    }
    att_kernel<<<gnode, 256, 0, stream>>>(als, ald, row_ptr, csr_src, alpha, L.H);
    agg_kernel<<<gnode, 256, 0, stream>>>(hA, alpha, row_ptr, csr_src, L.b, hB, L.H, L.C);
  }

  // ---- pooling ----
  hipMemsetAsync(pooled, 0, sizeof(float) * NB * 570, stream);
  pool_kernel<<<gnode, 256, 0, stream>>>(hB, batch, pooled, 570);

  // ---- head MLP (split-K; hA reused as partial buffer, node phase is done) ----
  float* partials = hA;  // max 16.8 MB needed, hA is 34.2 MB
  auto gemm_sk = [&](const float* A, const float* W, const float* bias, float* C,
                     int M, int K, int N, int relu, int S) {
    int kchunk = ((K + 16 * S - 1) / (16 * S)) * 16;   // multiple of 16, S*kchunk >= K
    dim3 g((N + 63) / 64, (M + 63) / 64, S);
    gemm_splitk_kernel<<<g, 256, 0, stream>>>(A, W, partials, M, K, N, kchunk);
    int MN = M * N;
    reduce_kernel<<<(MN + 255) / 256, 256, 0, stream>>>(partials, bias, C, MN, N, S, relu);
  };
  gemm_sk(pooled, Wg, bg, gbuf, NB, 570, 1024, 0, 8);
  {
    int tot = NB * (1024 + DESCD);
    concat_kernel<<<(tot + 255) / 256, 256, 0, stream>>>(gbuf, desc, zbuf);
  }
  gemm_sk(zbuf, Wf1, bf1, t1, NB, 1024 + DESCD, 1024, 1, 16);
  gemm_sk(t1,   Wf2, bf2, t2, NB, 1024, 2048, 1, 8);
  gemm_sk(t2,   Wf3, bf3, t1, NB, 2048, 1024, 1, 16);
  gemm_sk(t1,   Wf4, bf4, t2, NB, 1024, 256, 1, 32);
  fc5_kernel<<<(NB + 3) / 4, 256, 0, stream>>>(t2, Wf5, bf5, out);
}

// Round 3
// 1314.379 us; speedup vs baseline: 2.2814x; 1.4490x over previous
//
#include <hip/hip_runtime.h>
#include <hip/hip_bf16.h>
#include <math.h>

// ---------------- model constants ----------------
#define NNODES 10000
#define NEDGES 160000
#define NB     256
#define ETOT   (NEDGES + NNODES)   // with self loops
#define INDIM  57
#define DESCD  1217

static inline size_t align256(size_t x) { return (x + 255) & ~size_t(255); }

// ---------------- wave helpers ----------------
__device__ inline float wave_max(float v) {
#pragma unroll
  for (int o = 32; o > 0; o >>= 1) v = fmaxf(v, __shfl_xor(v, o));
  return v;
}
__device__ inline float wave_sum(float v) {
#pragma unroll
  for (int o = 32; o > 0; o >>= 1) v += __shfl_xor(v, o);
  return v;
}

// ---------------- CSR build ----------------
__global__ void count_kernel(const int* __restrict__ ei, int* __restrict__ deg) {
  int e = blockIdx.x * blockDim.x + threadIdx.x;
  if (e < ETOT) {
    int dst = (e < NEDGES) ? ei[NEDGES + e] : (e - NEDGES);
    atomicAdd(&deg[dst], 1);
  }
}

__global__ __launch_bounds__(1024) void scan_kernel(const int* __restrict__ deg,
                                                    int* __restrict__ row_ptr,
                                                    int* __restrict__ cursor) {
  __shared__ int part[1024];
  const int CHUNK = (NNODES + 1023) / 1024;  // 10
  int t = threadIdx.x;
  int start = t * CHUNK;
  int sum = 0;
  for (int i = 0; i < CHUNK; ++i) {
    int idx = start + i;
    if (idx < NNODES) sum += deg[idx];
  }
  part[t] = sum;
  __syncthreads();
  for (int off = 1; off < 1024; off <<= 1) {
    int v = (t >= off) ? part[t - off] : 0;
    __syncthreads();
    part[t] += v;
    __syncthreads();
  }
  int run = (t > 0) ? part[t - 1] : 0;
  for (int i = 0; i < CHUNK; ++i) {
    int idx = start + i;
    if (idx < NNODES) {
      row_ptr[idx] = run;
      cursor[idx] = run;
      run += deg[idx];
    }
  }
  if (t == 1023) row_ptr[NNODES] = ETOT;
}

__global__ void scatter_kernel(const int* __restrict__ ei, int* __restrict__ cursor,
                               int* __restrict__ csr_src) {
  int e = blockIdx.x * blockDim.x + threadIdx.x;
  if (e < ETOT) {
    int src, dst;
    if (e < NEDGES) { src = ei[e]; dst = ei[NEDGES + e]; }
    else            { src = e - NEDGES; dst = src; }
    int idx = atomicAdd(&cursor[dst], 1);
    csr_src[idx] = src;
  }
}

// ---------------- generic fp32 GEMM: C = A[M,K](lda) @ W[K,N] (+bias,relu), C stride ldc ----------------
__global__ __launch_bounds__(256) void gemm_kernel(const float* __restrict__ A,
                                                   const float* __restrict__ W,
                                                   const float* __restrict__ bias,
                                                   float* __restrict__ Cm,
                                                   int M, int K, int N, int relu,
                                                   int lda, int ldc) {
  __shared__ float As[16][65];
  __shared__ float Bs[16][65];
  int tid = threadIdx.x;
  int tx = tid % 16, ty = tid / 16;
  int m0 = blockIdx.y * 64, n0 = blockIdx.x * 64;
  float acc[4][4] = {};
  for (int k0 = 0; k0 < K; k0 += 16) {
    {
      int c = tid % 16;
      int r = tid / 16;
#pragma unroll
      for (int i = 0; i < 4; ++i) {
        int rr = r + i * 16;
        int gm = m0 + rr, gk = k0 + c;
        As[c][rr] = (gm < M && gk < K) ? A[(size_t)gm * lda + gk] : 0.f;
      }
      int nn = tid % 64;
      int kk = tid / 64;
#pragma unroll
      for (int i = 0; i < 4; ++i) {
        int kkk = kk + i * 4;
        int gk = k0 + kkk, gn = n0 + nn;
        Bs[kkk][nn] = (gk < K && gn < N) ? W[(size_t)gk * N + gn] : 0.f;
      }
    }
    __syncthreads();
#pragma unroll
    for (int kk = 0; kk < 16; ++kk) {
      float a[4], b[4];
#pragma unroll
      for (int i = 0; i < 4; ++i) a[i] = As[kk][ty * 4 + i];
#pragma unroll
      for (int j = 0; j < 4; ++j) b[j] = Bs[kk][tx * 4 + j];
#pragma unroll
      for (int i = 0; i < 4; ++i)
#pragma unroll
        for (int j = 0; j < 4; ++j) acc[i][j] += a[i] * b[j];
    }
    __syncthreads();
  }
#pragma unroll
  for (int i = 0; i < 4; ++i) {
    int gm = m0 + ty * 4 + i;
    if (gm >= M) continue;
#pragma unroll
    for (int j = 0; j < 4; ++j) {
      int gn = n0 + tx * 4 + j;
      if (gn >= N) continue;
      float v = acc[i][j] + (bias ? bias[gn] : 0.f);
      if (relu) v = fmaxf(v, 0.f);
      Cm[(size_t)gm * ldc + gn] = v;
    }
  }
}

// ---------------- split-K fp32 GEMM: P[z] = A[M,Kc] @ W[Kc,N] partials (contiguous A,C) ----------------
__global__ __launch_bounds__(256) void gemm_splitk_kernel(const float* __restrict__ A,
                                                          const float* __restrict__ W,
                                                          float* __restrict__ P,
                                                          int M, int K, int N, int kchunk) {
  __shared__ float As[16][65];
  __shared__ float Bs[16][65];
  int tid = threadIdx.x;
  int tx = tid % 16, ty = tid / 16;
  int m0 = blockIdx.y * 64, n0 = blockIdx.x * 64;
  int z = blockIdx.z;
  int kb = z * kchunk;
  int ke = min(K, kb + kchunk);
  float acc[4][4] = {};
  for (int k0 = kb; k0 < ke; k0 += 16) {
    {
      int c = tid % 16;
      int r = tid / 16;
#pragma unroll
      for (int i = 0; i < 4; ++i) {
        int rr = r + i * 16;
        int gm = m0 + rr, gk = k0 + c;
        As[c][rr] = (gm < M && gk < ke) ? A[(size_t)gm * K + gk] : 0.f;
      }
      int nn = tid % 64;
      int kk = tid / 64;
#pragma unroll
      for (int i = 0; i < 4; ++i) {
        int kkk = kk + i * 4;
        int gk = k0 + kkk, gn = n0 + nn;
        Bs[kkk][nn] = (gk < ke && gn < N) ? W[(size_t)gk * N + gn] : 0.f;
      }
    }
    __syncthreads();
#pragma unroll
    for (int kk = 0; kk < 16; ++kk) {
      float a[4], b[4];
#pragma unroll
      for (int i = 0; i < 4; ++i) a[i] = As[kk][ty * 4 + i];
#pragma unroll
      for (int j = 0; j < 4; ++j) b[j] = Bs[kk][tx * 4 + j];
#pragma unroll
      for (int i = 0; i < 4; ++i)
#pragma unroll
        for (int j = 0; j < 4; ++j) acc[i][j] += a[i] * b[j];
    }
    __syncthreads();
  }
  size_t base = (size_t)z * M * N;
#pragma unroll
  for (int i = 0; i < 4; ++i) {
    int gm = m0 + ty * 4 + i;
    if (gm >= M) continue;
#pragma unroll
    for (int j = 0; j < 4; ++j) {
      int gn = n0 + tx * 4 + j;
      if (gn >= N) continue;
      P[base + (size_t)gm * N + gn] = acc[i][j];
    }
  }
}

// ---------------- split-K reduce (+bias, opt relu) ----------------
__global__ void reduce_kernel(const float* __restrict__ P, const float* __restrict__ bias,
                              float* __restrict__ C, int MN, int N, int S, int relu) {
  int i = blockIdx.x * blockDim.x + threadIdx.x;
  if (i >= MN) return;
  float s = bias[i % N];
  for (int z = 0; z < S; ++z) s += P[(size_t)z * MN + i];
  C[i] = relu ? fmaxf(s, 0.f) : s;
}

// ---------------- FC5: [256,256] @ [256,1] wave-dot ----------------
__global__ __launch_bounds__(256) void fc5_kernel(const float* __restrict__ A,
                                                  const float* __restrict__ w,
                                                  const float* __restrict__ b,
                                                  float* __restrict__ out) {
  int wid = threadIdx.x >> 6, lane = threadIdx.x & 63;
  int m = blockIdx.x * 4 + wid;
  if (m >= NB) return;
  float s = 0.f;
  for (int k = lane; k < 256; k += 64) s += A[m * 256 + k] * w[k];
  s = wave_sum(s);
  if (lane == 0) out[m] = s + b[0];
}

// ---------------- attention logit dots: als/ald [N,H] ----------------
__global__ __launch_bounds__(256) void al_kernel(const float* __restrict__ hbuf,
                                                 const float* __restrict__ a_s,
                                                 const float* __restrict__ a_d,
                                                 float* __restrict__ als,
                                                 float* __restrict__ ald,
                                                 int H, int C, int ldh) {
  int wid = threadIdx.x >> 6, lane = threadIdx.x & 63;
  int g = blockIdx.x * 4 + wid;
  if (g >= NNODES * H) return;
  int n = g / H, h = g % H;
  const float* hr = hbuf + (size_t)n * ldh + (size_t)h * C;
  float ss = 0.f, sd = 0.f;
  for (int c = lane; c < C; c += 64) {
    float v = hr[c];
    ss += v * a_s[h * C + c];
    sd += v * a_d[h * C + c];
  }
  ss = wave_sum(ss);
  sd = wave_sum(sd);
  if (lane == 0) { als[g] = ss; ald[g] = sd; }
}

// ---------------- per-node segment softmax -> alpha per CSR slot ----------------
__global__ __launch_bounds__(256) void att_kernel(const float* __restrict__ als,
                                                  const float* __restrict__ ald,
                                                  const int* __restrict__ row_ptr,
                                                  const int* __restrict__ csr_src,
                                                  float* __restrict__ alpha, int H) {
  int wid = threadIdx.x >> 6, lane = threadIdx.x & 63;
  int n = blockIdx.x * 4 + wid;
  if (n >= NNODES) return;
  int rp = row_ptr[n], deg = row_ptr[n + 1] - rp;
  for (int h = 0; h < H; ++h) {
    float ad = ald[n * H + h];
    float m = -1e30f;
    for (int j = lane; j < deg; j += 64) {
      int s = csr_src[rp + j];
      float e = als[s * H + h] + ad;
      e = (e >= 0.f) ? e : 0.2f * e;
      m = fmaxf(m, e);
    }
    m = wave_max(m);
    float ssum = 0.f;
    for (int j = lane; j < deg; j += 64) {
      int s = csr_src[rp + j];
      float e = als[s * H + h] + ad;
      e = (e >= 0.f) ? e : 0.2f * e;
      ssum += expf(e - m);
    }
    ssum = wave_sum(ssum);
    float inv = 1.f / (ssum + 1e-16f);
    for (int j = lane; j < deg; j += 64) {
      int s = csr_src[rp + j];
      float e = als[s * H + h] + ad;
      e = (e >= 0.f) ? e : 0.2f * e;
      alpha[(size_t)(rp + j) * H + h] = expf(e - m) * inv;
    }
  }
}

// ---------------- message aggregation + bias + relu (wave per node×chunk, float4) ----------------
__global__ __launch_bounds__(256) void agg_kernel(const float* __restrict__ hbuf,
                                                  const float* __restrict__ alpha,
                                                  const int* __restrict__ row_ptr,
                                                  const int* __restrict__ csr_src,
                                                  const float* __restrict__ bias,
                                                  float* __restrict__ out,
                                                  int H, int C, int ldh, int nchunks) {
  int wid = threadIdx.x >> 6, lane = threadIdx.x & 63;
  int gw = blockIdx.x * 4 + wid;
  int n = gw / nchunks, chunk = gw - n * nchunks;
  if (n >= NNODES) return;
  int HC = H * C;
  int k0 = chunk * 256 + lane * 4;
  if (k0 >= HC) return;
  // loop-invariant head selection for the 4 elements (at most 2 distinct heads)
  int h0 = k0 / C;
  int h1 = min(k0 + 3, HC - 1) / C;
  int split = (h0 + 1) * C;  // k < split -> head h0, else h1
  bool u0 = (k0 + 0) < split, u1 = (k0 + 1) < split,
       u2 = (k0 + 2) < split, u3 = (k0 + 3) < split;
  int rp = row_ptr[n], deg = row_ptr[n + 1] - rp;
  float ax = 0.f, ay = 0.f, az = 0.f, aw = 0.f;
#pragma unroll 2
  for (int j = 0; j < deg; ++j) {
    int e = rp + j;
    int s = csr_src[e];
    float a0 = alpha[(size_t)e * H + h0];
    float a1 = alpha[(size_t)e * H + h1];
    float4 v = *reinterpret_cast<const float4*>(hbuf + (size_t)s * ldh + k0);
    ax += (u0 ? a0 : a1) * v.x;
    ay += (u1 ? a0 : a1) * v.y;
    az += (u2 ? a0 : a1) * v.z;
    aw += (u3 ? a0 : a1) * v.w;
  }
  size_t ob = (size_t)n * ldh + k0;
  out[ob + 0] = fmaxf(ax + bias[k0 + 0], 0.f);
  if (k0 + 1 < HC) out[ob + 1] = fmaxf(ay + bias[k0 + 1], 0.f);
  if (k0 + 2 < HC) out[ob + 2] = fmaxf(az + bias[k0 + 2], 0.f);
  if (k0 + 3 < HC) out[ob + 3] = fmaxf(aw + bias[k0 + 3], 0.f);
}

// ---------------- global add pool ----------------
__global__ __launch_bounds__(256) void pool_kernel(const float* __restrict__ h4,
                                                   const int* __restrict__ batch,
                                                   float* __restrict__ pooled, int F, int ldh) {
  int wid = threadIdx.x >> 6, lane = threadIdx.x & 63;
  int n = blockIdx.x * 4 + wid;
  if (n >= NNODES) return;
  int b = batch[n];
  for (int k = lane; k < F; k += 64) atomicAdd(&pooled[(size_t)b * F + k], h4[(size_t)n * ldh + k]);
}

// ---------------- concat [g | desc] ----------------
__global__ void concat_kernel(const float* __restrict__ g, const float* __restrict__ desc,
                              float* __restrict__ z) {
  const int W = 1024 + DESCD;
  int idx = blockIdx.x * blockDim.x + threadIdx.x;
  if (idx < NB * W) {
    int b = idx / W, c = idx % W;
    z[idx] = (c < 1024) ? g[b * 1024 + c] : desc[b * DESCD + (c - 1024)];
  }
}

// ---------------- launch ----------------
extern "C" void kernel_launch(void* const* d_in, const int* in_sizes, int n_in,
                              void* d_out, int out_size, void* d_ws, size_t ws_size,
                              hipStream_t stream) {
  const float* x    = (const float*)d_in[0];
  const int*   ei   = (const int*)d_in[1];
  const int*   batch= (const int*)d_in[2];
  const float* desc = (const float*)d_in[3];
  const float* W1 = (const float*)d_in[4];  const float* as1 = (const float*)d_in[5];
  const float* ad1 = (const float*)d_in[6]; const float* b1 = (const float*)d_in[7];
  const float* W2 = (const float*)d_in[8];  const float* as2 = (const float*)d_in[9];
  const float* ad2 = (const float*)d_in[10];const float* b2 = (const float*)d_in[11];
  const float* W3 = (const float*)d_in[12]; const float* as3 = (const float*)d_in[13];
  const float* ad3 = (const float*)d_in[14];const float* b3 = (const float*)d_in[15];
  const float* W4 = (const float*)d_in[16]; const float* as4 = (const float*)d_in[17];
  const float* ad4 = (const float*)d_in[18];const float* b4 = (const float*)d_in[19];
  const float* Wg = (const float*)d_in[20]; const float* bg = (const float*)d_in[21];
  const float* Wf1 = (const float*)d_in[22];const float* bf1 = (const float*)d_in[23];
  const float* Wf2 = (const float*)d_in[24];const float* bf2 = (const float*)d_in[25];
  const float* Wf3 = (const float*)d_in[26];const float* bf3 = (const float*)d_in[27];
  const float* Wf4 = (const float*)d_in[28];const float* bf4 = (const float*)d_in[29];
  const float* Wf5 = (const float*)d_in[30];const float* bf5 = (const float*)d_in[31];
  float* out = (float*)d_out;

  // ---- workspace carve-up ----
  char* p = (char*)d_ws;
  size_t off = 0;
  auto alloc = [&](size_t bytes) -> char* {
    char* r = p + off;
    off = align256(off + bytes);
    return r;
  };
  const int LDMAX = 856;  // padded stride for 855; 570 pads to 572
  int*   deg     = (int*)alloc(sizeof(int) * NNODES);
  int*   row_ptr = (int*)alloc(sizeof(int) * (NNODES + 1));
  int*   cursor  = (int*)alloc(sizeof(int) * NNODES);
  int*   csr_src = (int*)alloc(sizeof(int) * ETOT);
  float* als     = (float*)alloc(sizeof(float) * NNODES * 5);
  float* ald     = (float*)alloc(sizeof(float) * NNODES * 5);
  float* alpha   = (float*)alloc(sizeof(float) * (size_t)ETOT * 5);
  float* hA      = (float*)alloc(sizeof(float) * ((size_t)NNODES * LDMAX + 1024));
  float* hB      = (float*)alloc(sizeof(float) * ((size_t)NNODES * LDMAX + 1024));
  float* pooled  = (float*)alloc(sizeof(float) * NB * 570);
  float* gbuf    = (float*)alloc(sizeof(float) * NB * 1024);
  float* zbuf    = (float*)alloc(sizeof(float) * NB * (1024 + DESCD));
  float* t1      = (float*)alloc(sizeof(float) * NB * 2048);
  float* t2      = (float*)alloc(sizeof(float) * NB * 2048);
  (void)ws_size;

  // ---- CSR build ----
  hipMemsetAsync(deg, 0, sizeof(int) * NNODES, stream);
  {
    dim3 g((ETOT + 255) / 256);
    count_kernel<<<g, 256, 0, stream>>>(ei, deg);
    scan_kernel<<<1, 1024, 0, stream>>>(deg, row_ptr, cursor);
    scatter_kernel<<<g, 256, 0, stream>>>(ei, cursor, csr_src);
  }

  dim3 gnode((NNODES + 3) / 4);

  // ---- GAT layers ----
  struct LayerDef { const float* in; const float* W; const float* a_s; const float* a_d;
                    const float* b; int K; int H; int C; int lda; int ldh; };
  LayerDef layers[4] = {
    { x,  W1, as1, ad1, b1, INDIM, 5, 114, INDIM, 572 },
    { hB, W2, as2, ad2, b2, 570,   5, 171, 572,   856 },
    { hB, W3, as3, ad3, b3, 855,   5, 114, 856,   572 },
    { hB, W4, as4, ad4, b4, 570,   1, 570, 572,   572 },
  };
  for (int l = 0; l < 4; ++l) {
    LayerDef& L = layers[l];
    int HC = L.H * L.C;
    {
      dim3 g((HC + 63) / 64, (NNODES + 63) / 64);
      gemm_kernel<<<g, 256, 0, stream>>>(L.in, L.W, nullptr, hA, NNODES, L.K, HC, 0,
                                         L.lda, L.ldh);
    }
    {
      dim3 g((NNODES * L.H + 3) / 4);
      al_kernel<<<g, 256, 0, stream>>>(hA, L.a_s, L.a_d, als, ald, L.H, L.C, L.ldh);
    }
    att_kernel<<<gnode, 256, 0, stream>>>(als, ald, row_ptr, csr_src, alpha, L.H);
    {
      int nchunks = (HC + 255) / 256;
      dim3 g((NNODES * nchunks + 3) / 4);
      agg_kernel<<<g, 256, 0, stream>>>(hA, alpha, row_ptr, csr_src, L.b, hB,
                                        L.H, L.C, L.ldh, nchunks);
    }
  }

  // ---- pooling ----
  hipMemsetAsync(pooled, 0, sizeof(float) * NB * 570, stream);
  pool_kernel<<<gnode, 256, 0, stream>>>(hB, batch, pooled, 570, 572);

  // ---- head MLP (split-K; hA reused as partial buffer, node phase is done) ----
  float* partials = hA;
  auto gemm_sk = [&](const float* A, const float* W, const float* bias, float* C,
                     int M, int K, int N, int relu, int S) {
    int kchunk = ((K + 16 * S - 1) / (16 * S)) * 16;
    dim3 g((N + 63) / 64, (M + 63) / 64, S);
    gemm_splitk_kernel<<<g, 256, 0, stream>>>(A, W, partials, M, K, N, kchunk);
    int MN = M * N;
    reduce_kernel<<<(MN + 255) / 256, 256, 0, stream>>>(partials, bias, C, MN, N, S, relu);
  };
  gemm_sk(pooled, Wg, bg, gbuf, NB, 570, 1024, 0, 8);
  {
    int tot = NB * (1024 + DESCD);
    concat_kernel<<<(tot + 255) / 256, 256, 0, stream>>>(gbuf, desc, zbuf);
  }
  gemm_sk(zbuf, Wf1, bf1, t1, NB, 1024 + DESCD, 1024, 1, 16);
  gemm_sk(t1,   Wf2, bf2, t2, NB, 1024, 2048, 1, 8);
  gemm_sk(t2,   Wf3, bf3, t1, NB, 2048, 1024, 1, 16);
  gemm_sk(t1,   Wf4, bf4, t2, NB, 1024, 256, 1, 32);
  fc5_kernel<<<(NB + 3) / 4, 256, 0, stream>>>(t2, Wf5, bf5, out);
}

// Round 4
// 649.551 us; speedup vs baseline: 4.6164x; 2.0235x over previous
//
#include <hip/hip_runtime.h>
#include <hip/hip_bf16.h>
#include <math.h>

// ---------------- model constants ----------------
#define NNODES 10000
#define NEDGES 160000
#define NB     256
#define ETOT   (NEDGES + NNODES)   // with self loops
#define INDIM  57
#define DESCD  1217

static inline size_t align256(size_t x) { return (x + 255) & ~size_t(255); }

typedef _Float16 half4_t __attribute__((ext_vector_type(4)));
typedef _Float16 half8_t __attribute__((ext_vector_type(8)));
typedef float f32x4 __attribute__((ext_vector_type(4)));

// ---------------- wave helpers ----------------
__device__ inline float wave_max(float v) {
#pragma unroll
  for (int o = 32; o > 0; o >>= 1) v = fmaxf(v, __shfl_xor(v, o));
  return v;
}
__device__ inline float wave_sum(float v) {
#pragma unroll
  for (int o = 32; o > 0; o >>= 1) v += __shfl_xor(v, o);
  return v;
}

// ---------------- CSR build ----------------
__global__ void count_kernel(const int* __restrict__ ei, int* __restrict__ deg) {
  int e = blockIdx.x * blockDim.x + threadIdx.x;
  if (e < ETOT) {
    int dst = (e < NEDGES) ? ei[NEDGES + e] : (e - NEDGES);
    atomicAdd(&deg[dst], 1);
  }
}

__global__ __launch_bounds__(1024) void scan_kernel(const int* __restrict__ deg,
                                                    int* __restrict__ row_ptr,
                                                    int* __restrict__ cursor) {
  __shared__ int part[1024];
  const int CHUNK = (NNODES + 1023) / 1024;  // 10
  int t = threadIdx.x;
  int start = t * CHUNK;
  int sum = 0;
  for (int i = 0; i < CHUNK; ++i) {
    int idx = start + i;
    if (idx < NNODES) sum += deg[idx];
  }
  part[t] = sum;
  __syncthreads();
  for (int off = 1; off < 1024; off <<= 1) {
    int v = (t >= off) ? part[t - off] : 0;
    __syncthreads();
    part[t] += v;
    __syncthreads();
  }
  int run = (t > 0) ? part[t - 1] : 0;
  for (int i = 0; i < CHUNK; ++i) {
    int idx = start + i;
    if (idx < NNODES) {
      row_ptr[idx] = run;
      cursor[idx] = run;
      run += deg[idx];
    }
  }
  if (t == 1023) row_ptr[NNODES] = ETOT;
}

__global__ void scatter_kernel(const int* __restrict__ ei, int* __restrict__ cursor,
                               int* __restrict__ csr_src) {
  int e = blockIdx.x * blockDim.x + threadIdx.x;
  if (e < ETOT) {
    int src, dst;
    if (e < NEDGES) { src = ei[e]; dst = ei[NEDGES + e]; }
    else            { src = e - NEDGES; dst = src; }
    int idx = atomicAdd(&cursor[dst], 1);
    csr_src[idx] = src;
  }
}

// ---------------- fp32 -> fp16 conversions ----------------
__global__ void convert_x_kernel(const float* __restrict__ x, _Float16* __restrict__ x16) {
  int t = blockIdx.x * blockDim.x + threadIdx.x;
  if (t >= NNODES * 64) return;
  int n = t >> 6, k = t & 63;
  x16[t] = (_Float16)((k < INDIM) ? x[n * INDIM + k] : 0.f);
}

// W [K][N] fp32 -> Wt [Npad][Kpad] fp16 (transposed, zero-padded)
__global__ void convert_wt_kernel(const float* __restrict__ W, _Float16* __restrict__ Wt,
                                  int K, int N, int Kpad, int Npad) {
  int t = blockIdx.x * blockDim.x + threadIdx.x;
  if (t >= Npad * Kpad) return;
  int n = t / Kpad, k = t - n * Kpad;
  float v = (n < N && k < K) ? W[(size_t)k * N + n] : 0.f;
  Wt[t] = (_Float16)v;
}

// ---------------- MFMA fp16 GEMM: C[M][ldc](fp16) = A[M][Kpad] @ Bt[Npad][Kpad]^T ----------------
// 128x128 tile, 4 waves (2x2), per-wave 64x64 = 4x4 frags of 16x16, BK=64.
// LDS layout: tile[r][kb] at byte r*128 + (kb ^ (r&7))*16  (16B-chunk XOR swizzle)
__global__ __launch_bounds__(256) void mfma_gemm_kernel(
    const _Float16* __restrict__ A, const _Float16* __restrict__ Bt,
    _Float16* __restrict__ C, int M, int Kpad, int Nreal, int ldc) {
  __shared__ __align__(16) char smem[32768];
  char* AsB = smem;
  char* BsB = smem + 16384;
  int tid = threadIdx.x;
  int lane = tid & 63, wid = tid >> 6;
  int l15 = lane & 15, g = lane >> 4;
  int wr = wid >> 1, wc = wid & 1;
  int m0 = blockIdx.y * 128, n0 = blockIdx.x * 128;
  f32x4 acc[4][4];
#pragma unroll
  for (int i = 0; i < 4; ++i)
#pragma unroll
    for (int j = 0; j < 4; ++j) acc[i][j] = (f32x4){0.f, 0.f, 0.f, 0.f};

  int KT = Kpad >> 6;
  half8_t pa[4], pb[4];
  // prefetch K-tile 0 (global -> regs)
#pragma unroll
  for (int i = 0; i < 4; ++i) {
    int r = i * 32 + (tid >> 3);
    int cs = (tid & 7) ^ (r & 7);
    int ga = min(m0 + r, M - 1);
    pa[i] = *(const half8_t*)(A + (size_t)ga * Kpad + cs * 8);
    pb[i] = *(const half8_t*)(Bt + (size_t)(n0 + r) * Kpad + cs * 8);
  }
  for (int kt = 0; kt < KT; ++kt) {
    __syncthreads();  // previous tile's compute done
#pragma unroll
    for (int i = 0; i < 4; ++i) {
      *(half8_t*)(AsB + i * 4096 + tid * 16) = pa[i];
      *(half8_t*)(BsB + i * 4096 + tid * 16) = pb[i];
    }
    __syncthreads();
    if (kt + 1 < KT) {
      int k0 = (kt + 1) << 6;
#pragma unroll
      for (int i = 0; i < 4; ++i) {
        int r = i * 32 + (tid >> 3);
        int cs = (tid & 7) ^ (r & 7);
        int ga = min(m0 + r, M - 1);
        pa[i] = *(const half8_t*)(A + (size_t)ga * Kpad + k0 + cs * 8);
        pb[i] = *(const half8_t*)(Bt + (size_t)(n0 + r) * Kpad + k0 + cs * 8);
      }
    }
#pragma unroll
    for (int kk = 0; kk < 2; ++kk) {
      half8_t af[4], bf[4];
#pragma unroll
      for (int f = 0; f < 4; ++f) {
        int ra = wr * 64 + f * 16 + l15;
        af[f] = *(const half8_t*)(AsB + ra * 128 + (((kk * 4 + g) ^ (ra & 7)) << 4));
        int cb = wc * 64 + f * 16 + l15;
        bf[f] = *(const half8_t*)(BsB + cb * 128 + (((kk * 4 + g) ^ (cb & 7)) << 4));
      }
#pragma unroll
      for (int fm = 0; fm < 4; ++fm)
#pragma unroll
        for (int fn = 0; fn < 4; ++fn)
          acc[fm][fn] = __builtin_amdgcn_mfma_f32_16x16x32_f16(af[fm], bf[fn], acc[fm][fn], 0, 0, 0);
    }
  }
  // store: D[row=4*(l>>4)+reg][col=l&15] per frag (m89-verified layout)
#pragma unroll
  for (int fm = 0; fm < 4; ++fm) {
    int gmb = m0 + wr * 64 + fm * 16 + g * 4;
#pragma unroll
    for (int fn = 0; fn < 4; ++fn) {
      int gn = n0 + wc * 64 + fn * 16 + l15;
      if (gn >= Nreal) continue;
#pragma unroll
      for (int j = 0; j < 4; ++j) {
        int gm = gmb + j;
        if (gm < M) C[(size_t)gm * ldc + gn] = (_Float16)acc[fm][fn][j];
      }
    }
  }
}

// ---------------- split-K fp32 GEMM (head MLP) ----------------
__global__ __launch_bounds__(256) void gemm_splitk_kernel(const float* __restrict__ A,
                                                          const float* __restrict__ W,
                                                          float* __restrict__ P,
                                                          int M, int K, int N, int kchunk) {
  __shared__ float As[16][65];
  __shared__ float Bs[16][65];
  int tid = threadIdx.x;
  int tx = tid % 16, ty = tid / 16;
  int m0 = blockIdx.y * 64, n0 = blockIdx.x * 64;
  int z = blockIdx.z;
  int kb = z * kchunk;
  int ke = min(K, kb + kchunk);
  float acc[4][4] = {};
  for (int k0 = kb; k0 < ke; k0 += 16) {
    {
      int c = tid % 16;
      int r = tid / 16;
#pragma unroll
      for (int i = 0; i < 4; ++i) {
        int rr = r + i * 16;
        int gm = m0 + rr, gk = k0 + c;
        As[c][rr] = (gm < M && gk < ke) ? A[(size_t)gm * K + gk] : 0.f;
      }
      int nn = tid % 64;
      int kk = tid / 64;
#pragma unroll
      for (int i = 0; i < 4; ++i) {
        int kkk = kk + i * 4;
        int gk = k0 + kkk, gn = n0 + nn;
        Bs[kkk][nn] = (gk < ke && gn < N) ? W[(size_t)gk * N + gn] : 0.f;
      }
    }
    __syncthreads();
#pragma unroll
    for (int kk = 0; kk < 16; ++kk) {
      float a[4], b[4];
#pragma unroll
      for (int i = 0; i < 4; ++i) a[i] = As[kk][ty * 4 + i];
#pragma unroll
      for (int j = 0; j < 4; ++j) b[j] = Bs[kk][tx * 4 + j];
#pragma unroll
      for (int i = 0; i < 4; ++i)
#pragma unroll
        for (int j = 0; j < 4; ++j) acc[i][j] += a[i] * b[j];
    }
    __syncthreads();
  }
  size_t base = (size_t)z * M * N;
#pragma unroll
  for (int i = 0; i < 4; ++i) {
    int gm = m0 + ty * 4 + i;
    if (gm >= M) continue;
#pragma unroll
    for (int j = 0; j < 4; ++j) {
      int gn = n0 + tx * 4 + j;
      if (gn >= N) continue;
      P[base + (size_t)gm * N + gn] = acc[i][j];
    }
  }
}

__global__ void reduce_kernel(const float* __restrict__ P, const float* __restrict__ bias,
                              float* __restrict__ C, int MN, int N, int S, int relu) {
  int i = blockIdx.x * blockDim.x + threadIdx.x;
  if (i >= MN) return;
  float s = bias[i % N];
  for (int z = 0; z < S; ++z) s += P[(size_t)z * MN + i];
  C[i] = relu ? fmaxf(s, 0.f) : s;
}

__global__ __launch_bounds__(256) void fc5_kernel(const float* __restrict__ A,
                                                  const float* __restrict__ w,
                                                  const float* __restrict__ b,
                                                  float* __restrict__ out) {
  int wid = threadIdx.x >> 6, lane = threadIdx.x & 63;
  int m = blockIdx.x * 4 + wid;
  if (m >= NB) return;
  float s = 0.f;
  for (int k = lane; k < 256; k += 64) s += A[m * 256 + k] * w[k];
  s = wave_sum(s);
  if (lane == 0) out[m] = s + b[0];
}

// ---------------- attention logit dots: als/ald [N,H] (fp16 h) ----------------
__global__ __launch_bounds__(256) void al_kernel(const _Float16* __restrict__ hbuf,
                                                 const float* __restrict__ a_s,
                                                 const float* __restrict__ a_d,
                                                 float* __restrict__ als,
                                                 float* __restrict__ ald,
                                                 int H, int C, int ldh) {
  int wid = threadIdx.x >> 6, lane = threadIdx.x & 63;
  int g = blockIdx.x * 4 + wid;
  if (g >= NNODES * H) return;
  int n = g / H, h = g % H;
  const _Float16* hr = hbuf + (size_t)n * ldh + (size_t)h * C;
  float ss = 0.f, sd = 0.f;
  for (int c = lane; c < C; c += 64) {
    float v = (float)hr[c];
    ss += v * a_s[h * C + c];
    sd += v * a_d[h * C + c];
  }
  ss = wave_sum(ss);
  sd = wave_sum(sd);
  if (lane == 0) { als[g] = ss; ald[g] = sd; }
}

// ---------------- per-node segment softmax -> alpha per CSR slot ----------------
__global__ __launch_bounds__(256) void att_kernel(const float* __restrict__ als,
                                                  const float* __restrict__ ald,
                                                  const int* __restrict__ row_ptr,
                                                  const int* __restrict__ csr_src,
                                                  float* __restrict__ alpha, int H) {
  int wid = threadIdx.x >> 6, lane = threadIdx.x & 63;
  int n = blockIdx.x * 4 + wid;
  if (n >= NNODES) return;
  int rp = row_ptr[n], deg = row_ptr[n + 1] - rp;
  for (int h = 0; h < H; ++h) {
    float ad = ald[n * H + h];
    float m = -1e30f;
    for (int j = lane; j < deg; j += 64) {
      int s = csr_src[rp + j];
      float e = als[s * H + h] + ad;
      e = (e >= 0.f) ? e : 0.2f * e;
      m = fmaxf(m, e);
    }
    m = wave_max(m);
    float ssum = 0.f;
    for (int j = lane; j < deg; j += 64) {
      int s = csr_src[rp + j];
      float e = als[s * H + h] + ad;
      e = (e >= 0.f) ? e : 0.2f * e;
      ssum += expf(e - m);
    }
    ssum = wave_sum(ssum);
    float inv = 1.f / (ssum + 1e-16f);
    for (int j = lane; j < deg; j += 64) {
      int s = csr_src[rp + j];
      float e = als[s * H + h] + ad;
      e = (e >= 0.f) ? e : 0.2f * e;
      alpha[(size_t)(rp + j) * H + h] = expf(e - m) * inv;
    }
  }
}

// ---------------- aggregation + bias + relu -> fp16 (next-layer GEMM input) ----------------
__global__ __launch_bounds__(256) void agg_kernel(const _Float16* __restrict__ hbuf,
                                                  const float* __restrict__ alpha,
                                                  const int* __restrict__ row_ptr,
                                                  const int* __restrict__ csr_src,
                                                  const float* __restrict__ bias,
                                                  _Float16* __restrict__ h16o,
                                                  int H, int C, int ldh, int ldo,
                                                  int HC, int nchunks) {
  int wid = threadIdx.x >> 6, lane = threadIdx.x & 63;
  int gw = blockIdx.x * 4 + wid;
  int n = gw / nchunks, chunk = gw - n * nchunks;
  if (n >= NNODES) return;
  int k0 = chunk * 256 + lane * 4;
  if (k0 >= ldo) return;
  _Float16* op = h16o + (size_t)n * ldo + k0;
  if (k0 >= HC) {  // pure zero-pad region
    half4_t z = {};
    *(half4_t*)op = z;
    return;
  }
  int h0 = k0 / C;
  int h1 = min(k0 + 3, HC - 1) / C;
  int split = (h0 + 1) * C;
  bool u0 = (k0 + 0) < split, u1 = (k0 + 1) < split,
       u2 = (k0 + 2) < split, u3 = (k0 + 3) < split;
  int rp = row_ptr[n], deg = row_ptr[n + 1] - rp;
  float ax = 0.f, ay = 0.f, az = 0.f, aw = 0.f;
#pragma unroll 2
  for (int j = 0; j < deg; ++j) {
    int e = rp + j;
    int s = csr_src[e];
    float a0 = alpha[(size_t)e * H + h0];
    float a1 = alpha[(size_t)e * H + h1];
    half4_t v = *(const half4_t*)(hbuf + (size_t)s * ldh + k0);
    ax += (u0 ? a0 : a1) * (float)v[0];
    ay += (u1 ? a0 : a1) * (float)v[1];
    az += (u2 ? a0 : a1) * (float)v[2];
    aw += (u3 ? a0 : a1) * (float)v[3];
  }
  half4_t o;
  o[0] = (_Float16)((k0 + 0 < HC) ? fmaxf(ax + bias[k0 + 0], 0.f) : 0.f);
  o[1] = (_Float16)((k0 + 1 < HC) ? fmaxf(ay + bias[k0 + 1], 0.f) : 0.f);
  o[2] = (_Float16)((k0 + 2 < HC) ? fmaxf(az + bias[k0 + 2], 0.f) : 0.f);
  o[3] = (_Float16)((k0 + 3 < HC) ? fmaxf(aw + bias[k0 + 3], 0.f) : 0.f);
  *(half4_t*)op = o;
}

// ---------------- global add pool (fp16 in, fp32 out) ----------------
__global__ __launch_bounds__(256) void pool_kernel(const _Float16* __restrict__ h4,
                                                   const int* __restrict__ batch,
                                                   float* __restrict__ pooled, int F, int ldh) {
  int wid = threadIdx.x >> 6, lane = threadIdx.x & 63;
  int n = blockIdx.x * 4 + wid;
  if (n >= NNODES) return;
  int b = batch[n];
  for (int k = lane; k < F; k += 64)
    atomicAdd(&pooled[(size_t)b * F + k], (float)h4[(size_t)n * ldh + k]);
}

// ---------------- concat [g | desc] ----------------
__global__ void concat_kernel(const float* __restrict__ g, const float* __restrict__ desc,
                              float* __restrict__ z) {
  const int W = 1024 + DESCD;
  int idx = blockIdx.x * blockDim.x + threadIdx.x;
  if (idx < NB * W) {
    int b = idx / W, c = idx % W;
    z[idx] = (c < 1024) ? g[b * 1024 + c] : desc[b * DESCD + (c - 1024)];
  }
}

// ---------------- launch ----------------
extern "C" void kernel_launch(void* const* d_in, const int* in_sizes, int n_in,
                              void* d_out, int out_size, void* d_ws, size_t ws_size,
                              hipStream_t stream) {
  const float* x    = (const float*)d_in[0];
  const int*   ei   = (const int*)d_in[1];
  const int*   batch= (const int*)d_in[2];
  const float* desc = (const float*)d_in[3];
  const float* W1 = (const float*)d_in[4];  const float* as1 = (const float*)d_in[5];
  const float* ad1 = (const float*)d_in[6]; const float* b1 = (const float*)d_in[7];
  const float* W2 = (const float*)d_in[8];  const float* as2 = (const float*)d_in[9];
  const float* ad2 = (const float*)d_in[10];const float* b2 = (const float*)d_in[11];
  const float* W3 = (const float*)d_in[12]; const float* as3 = (const float*)d_in[13];
  const float* ad3 = (const float*)d_in[14];const float* b3 = (const float*)d_in[15];
  const float* W4 = (const float*)d_in[16]; const float* as4 = (const float*)d_in[17];
  const float* ad4 = (const float*)d_in[18];const float* b4 = (const float*)d_in[19];
  const float* Wg = (const float*)d_in[20]; const float* bg = (const float*)d_in[21];
  const float* Wf1 = (const float*)d_in[22];const float* bf1 = (const float*)d_in[23];
  const float* Wf2 = (const float*)d_in[24];const float* bf2 = (const float*)d_in[25];
  const float* Wf3 = (const float*)d_in[26];const float* bf3 = (const float*)d_in[27];
  const float* Wf4 = (const float*)d_in[28];const float* bf4 = (const float*)d_in[29];
  const float* Wf5 = (const float*)d_in[30];const float* bf5 = (const float*)d_in[31];
  float* out = (float*)d_out;

  // ---- workspace carve-up ----
  char* p = (char*)d_ws;
  size_t off = 0;
  auto alloc = [&](size_t bytes) -> char* {
    char* r = p + off;
    off = align256(off + bytes);
    return r;
  };
  int*      deg     = (int*)alloc(sizeof(int) * NNODES);
  int*      row_ptr = (int*)alloc(sizeof(int) * (NNODES + 1));
  int*      cursor  = (int*)alloc(sizeof(int) * NNODES);
  int*      csr_src = (int*)alloc(sizeof(int) * ETOT);
  float*    als     = (float*)alloc(sizeof(float) * NNODES * 5);
  float*    ald     = (float*)alloc(sizeof(float) * NNODES * 5);
  float*    alpha   = (float*)alloc(sizeof(float) * (size_t)ETOT * 5);
  _Float16* x16     = (_Float16*)alloc(sizeof(_Float16) * (size_t)NNODES * 64);
  _Float16* hA16    = (_Float16*)alloc(sizeof(_Float16) * ((size_t)NNODES * 856 + 1024));  // GEMM out; head split-K partials later
  _Float16* h16     = (_Float16*)alloc(sizeof(_Float16) * ((size_t)NNODES * 896 + 1024));  // agg out / next GEMM in
  _Float16* Wt      = (_Float16*)alloc(sizeof(_Float16) * 896 * 896);
  float*    pooled  = (float*)alloc(sizeof(float) * NB * 570);
  float*    gbuf    = (float*)alloc(sizeof(float) * NB * 1024);
  float*    zbuf    = (float*)alloc(sizeof(float) * NB * (1024 + DESCD));
  float*    t1      = (float*)alloc(sizeof(float) * NB * 2048);
  float*    t2      = (float*)alloc(sizeof(float) * NB * 2048);
  (void)ws_size;

  // ---- CSR build ----
  hipMemsetAsync(deg, 0, sizeof(int) * NNODES, stream);
  {
    dim3 g((ETOT + 255) / 256);
    count_kernel<<<g, 256, 0, stream>>>(ei, deg);
    scan_kernel<<<1, 1024, 0, stream>>>(deg, row_ptr, cursor);
    scatter_kernel<<<g, 256, 0, stream>>>(ei, cursor, csr_src);
  }
  convert_x_kernel<<<(NNODES * 64 + 255) / 256, 256, 0, stream>>>(x, x16);

  dim3 gnode((NNODES + 3) / 4);

  // ---- GAT layers (fp16 MFMA node GEMMs) ----
  struct LayerDef { const float* W; const float* a_s; const float* a_d; const float* b;
                    int K; int H; int C; int Kpad; int Npad; int ldh; int ldo; };
  LayerDef L[4] = {
    { W1, as1, ad1, b1, INDIM, 5, 114,  64, 640, 572, 576 },
    { W2, as2, ad2, b2, 570,   5, 171, 576, 896, 856, 896 },
    { W3, as3, ad3, b3, 855,   5, 114, 896, 640, 572, 576 },
    { W4, as4, ad4, b4, 570,   1, 570, 576, 640, 572, 576 },
  };
  for (int l = 0; l < 4; ++l) {
    int HC = L[l].H * L[l].C;
    // weight transpose+convert
    {
      int tot = L[l].Npad * L[l].Kpad;
      convert_wt_kernel<<<(tot + 255) / 256, 256, 0, stream>>>(L[l].W, Wt, L[l].K, HC,
                                                               L[l].Kpad, L[l].Npad);
    }
    // h = in @ W  (fp16 MFMA)
    {
      const _Float16* Ain = (l == 0) ? x16 : h16;
      dim3 g(L[l].Npad / 128, (NNODES + 127) / 128);
      mfma_gemm_kernel<<<g, 256, 0, stream>>>(Ain, Wt, hA16, NNODES, L[l].Kpad, HC, L[l].ldh);
    }
    // attention logits
    {
      dim3 g((NNODES * L[l].H + 3) / 4);
      al_kernel<<<g, 256, 0, stream>>>(hA16, L[l].a_s, L[l].a_d, als, ald, L[l].H, L[l].C, L[l].ldh);
    }
    att_kernel<<<gnode, 256, 0, stream>>>(als, ald, row_ptr, csr_src, alpha, L[l].H);
    {
      int nchunks = (L[l].ldo + 255) / 256;
      dim3 g((NNODES * nchunks + 3) / 4);
      agg_kernel<<<g, 256, 0, stream>>>(hA16, alpha, row_ptr, csr_src, L[l].b, h16,
                                        L[l].H, L[l].C, L[l].ldh, L[l].ldo, HC, nchunks);
    }
  }

  // ---- pooling (layer-4 h16, stride 576, 570 cols) ----
  hipMemsetAsync(pooled, 0, sizeof(float) * NB * 570, stream);
  pool_kernel<<<gnode, 256, 0, stream>>>(h16, batch, pooled, 570, 576);

  // ---- head MLP (fp32 split-K; hA16 region reused as partials) ----
  float* partials = (float*)hA16;
  auto gemm_sk = [&](const float* A, const float* W, const float* bias, float* C,
                     int M, int K, int N, int relu, int S) {
    int kchunk = ((K + 16 * S - 1) / (16 * S)) * 16;
    dim3 g((N + 63) / 64, (M + 63) / 64, S);
    gemm_splitk_kernel<<<g, 256, 0, stream>>>(A, W, partials, M, K, N, kchunk);
    int MN = M * N;
    reduce_kernel<<<(MN + 255) / 256, 256, 0, stream>>>(partials, bias, C, MN, N, S, relu);
  };
  gemm_sk(pooled, Wg, bg, gbuf, NB, 570, 1024, 0, 8);
  {
    int tot = NB * (1024 + DESCD);
    concat_kernel<<<(tot + 255) / 256, 256, 0, stream>>>(gbuf, desc, zbuf);
  }
  gemm_sk(zbuf, Wf1, bf1, t1, NB, 1024 + DESCD, 1024, 1, 16);
  gemm_sk(t1,   Wf2, bf2, t2, NB, 1024, 2048, 1, 8);
  gemm_sk(t2,   Wf3, bf3, t1, NB, 2048, 1024, 1, 16);
  gemm_sk(t1,   Wf4, bf4, t2, NB, 1024, 256, 1, 32);
  fc5_kernel<<<(NB + 3) / 4, 256, 0, stream>>>(t2, Wf5, bf5, out);
}

// Round 5
// 539.284 us; speedup vs baseline: 5.5604x; 1.2045x over previous
//
#include <hip/hip_runtime.h>
#include <hip/hip_bf16.h>
#include <math.h>

// ---------------- model constants ----------------
#define NNODES 10000
#define NEDGES 160000
#define NB     256
#define ETOT   (NEDGES + NNODES)   // with self loops
#define INDIM  57
#define DESCD  1217

static inline size_t align256(size_t x) { return (x + 255) & ~size_t(255); }

typedef _Float16 half8_t __attribute__((ext_vector_type(8)));
typedef float f32x4 __attribute__((ext_vector_type(4)));

// ---------------- wave helpers ----------------
__device__ inline float wave_max(float v) {
#pragma unroll
  for (int o = 32; o > 0; o >>= 1) v = fmaxf(v, __shfl_xor(v, o));
  return v;
}
__device__ inline float wave_sum(float v) {
#pragma unroll
  for (int o = 32; o > 0; o >>= 1) v += __shfl_xor(v, o);
  return v;
}

// ---------------- CSR build ----------------
__global__ void count_kernel(const int* __restrict__ ei, int* __restrict__ deg) {
  int e = blockIdx.x * blockDim.x + threadIdx.x;
  if (e < ETOT) {
    int dst = (e < NEDGES) ? ei[NEDGES + e] : (e - NEDGES);
    atomicAdd(&deg[dst], 1);
  }
}

__global__ __launch_bounds__(1024) void scan_kernel(const int* __restrict__ deg,
                                                    int* __restrict__ row_ptr,
                                                    int* __restrict__ cursor) {
  __shared__ int part[1024];
  const int CHUNK = (NNODES + 1023) / 1024;  // 10
  int t = threadIdx.x;
  int start = t * CHUNK;
  int sum = 0;
  for (int i = 0; i < CHUNK; ++i) {
    int idx = start + i;
    if (idx < NNODES) sum += deg[idx];
  }
  part[t] = sum;
  __syncthreads();
  for (int off = 1; off < 1024; off <<= 1) {
    int v = (t >= off) ? part[t - off] : 0;
    __syncthreads();
    part[t] += v;
    __syncthreads();
  }
  int run = (t > 0) ? part[t - 1] : 0;
  for (int i = 0; i < CHUNK; ++i) {
    int idx = start + i;
    if (idx < NNODES) {
      row_ptr[idx] = run;
      cursor[idx] = run;
      run += deg[idx];
    }
  }
  if (t == 1023) row_ptr[NNODES] = ETOT;
}

__global__ void scatter_kernel(const int* __restrict__ ei, int* __restrict__ cursor,
                               int* __restrict__ csr_src) {
  int e = blockIdx.x * blockDim.x + threadIdx.x;
  if (e < ETOT) {
    int src, dst;
    if (e < NEDGES) { src = ei[e]; dst = ei[NEDGES + e]; }
    else            { src = e - NEDGES; dst = src; }
    int idx = atomicAdd(&cursor[dst], 1);
    csr_src[idx] = src;
  }
}

// ---------------- fp32 -> fp16 conversions ----------------
__global__ void convert_x_kernel(const float* __restrict__ x, _Float16* __restrict__ x16) {
  int t = blockIdx.x * blockDim.x + threadIdx.x;
  if (t >= NNODES * 64) return;
  int n = t >> 6, k = t & 63;
  x16[t] = (_Float16)((k < INDIM) ? x[n * INDIM + k] : 0.f);
}

// W [K][N] fp32 -> Wt [Npad][Kpad] fp16 (transposed, zero-padded)
__global__ void convert_wt_kernel(const float* __restrict__ W, _Float16* __restrict__ Wt,
                                  int K, int N, int Kpad, int Npad) {
  int t = blockIdx.x * blockDim.x + threadIdx.x;
  if (t >= Npad * Kpad) return;
  int n = t / Kpad, k = t - n * Kpad;
  float v = (n < N && k < K) ? W[(size_t)k * N + n] : 0.f;
  Wt[t] = (_Float16)v;
}

__global__ void pooled16_kernel(const float* __restrict__ pooled, _Float16* __restrict__ p16) {
  int t = blockIdx.x * blockDim.x + threadIdx.x;
  if (t >= NB * 576) return;
  int b = t / 576, c = t - b * 576;
  p16[t] = (_Float16)((c < 570) ? pooled[b * 570 + c] : 0.f);
}

// fill z16 cols [1024, 2304): desc then zero pad
__global__ void desc_fill_kernel(const float* __restrict__ desc, _Float16* __restrict__ z16) {
  int t = blockIdx.x * blockDim.x + threadIdx.x;
  if (t >= NB * 1280) return;
  int b = t / 1280, i = t - b * 1280;
  z16[(size_t)b * 2304 + 1024 + i] = (_Float16)((i < DESCD) ? desc[b * DESCD + i] : 0.f);
}

// ---------------- MFMA fp16 GEMM: C[M][ldc](fp16) = A[M][Kpad] @ Bt[Npad][Kpad]^T ----------------
// 128x128 tile, 4 waves (2x2), per-wave 64x64 = 4x4 frags of 16x16, BK=64.
// LDS layout: tile[r][kb] at byte r*128 + (kb ^ (r&7))*16  (16B-chunk XOR swizzle)
__global__ __launch_bounds__(256) void mfma_gemm_kernel(
    const _Float16* __restrict__ A, const _Float16* __restrict__ Bt,
    _Float16* __restrict__ C, int M, int Kpad, int Nreal, int ldc) {
  __shared__ __align__(16) char smem[32768];
  char* AsB = smem;
  char* BsB = smem + 16384;
  int tid = threadIdx.x;
  int lane = tid & 63, wid = tid >> 6;
  int l15 = lane & 15, g = lane >> 4;
  int wr = wid >> 1, wc = wid & 1;
  int m0 = blockIdx.y * 128, n0 = blockIdx.x * 128;
  f32x4 acc[4][4];
#pragma unroll
  for (int i = 0; i < 4; ++i)
#pragma unroll
    for (int j = 0; j < 4; ++j) acc[i][j] = (f32x4){0.f, 0.f, 0.f, 0.f};

  int KT = Kpad >> 6;
  half8_t pa[4], pb[4];
#pragma unroll
  for (int i = 0; i < 4; ++i) {
    int r = i * 32 + (tid >> 3);
    int cs = (tid & 7) ^ (r & 7);
    int ga = min(m0 + r, M - 1);
    pa[i] = *(const half8_t*)(A + (size_t)ga * Kpad + cs * 8);
    pb[i] = *(const half8_t*)(Bt + (size_t)(n0 + r) * Kpad + cs * 8);
  }
  for (int kt = 0; kt < KT; ++kt) {
    __syncthreads();
#pragma unroll
    for (int i = 0; i < 4; ++i) {
      *(half8_t*)(AsB + i * 4096 + tid * 16) = pa[i];
      *(half8_t*)(BsB + i * 4096 + tid * 16) = pb[i];
    }
    __syncthreads();
    if (kt + 1 < KT) {
      int k0 = (kt + 1) << 6;
#pragma unroll
      for (int i = 0; i < 4; ++i) {
        int r = i * 32 + (tid >> 3);
        int cs = (tid & 7) ^ (r & 7);
        int ga = min(m0 + r, M - 1);
        pa[i] = *(const half8_t*)(A + (size_t)ga * Kpad + k0 + cs * 8);
        pb[i] = *(const half8_t*)(Bt + (size_t)(n0 + r) * Kpad + k0 + cs * 8);
      }
    }
#pragma unroll
    for (int kk = 0; kk < 2; ++kk) {
      half8_t af[4], bf[4];
#pragma unroll
      for (int f = 0; f < 4; ++f) {
        int ra = wr * 64 + f * 16 + l15;
        af[f] = *(const half8_t*)(AsB + ra * 128 + (((kk * 4 + g) ^ (ra & 7)) << 4));
        int cb = wc * 64 + f * 16 + l15;
        bf[f] = *(const half8_t*)(BsB + cb * 128 + (((kk * 4 + g) ^ (cb & 7)) << 4));
      }
#pragma unroll
      for (int fm = 0; fm < 4; ++fm)
#pragma unroll
        for (int fn = 0; fn < 4; ++fn)
          acc[fm][fn] = __builtin_amdgcn_mfma_f32_16x16x32_f16(af[fm], bf[fn], acc[fm][fn], 0, 0, 0);
    }
  }
#pragma unroll
  for (int fm = 0; fm < 4; ++fm) {
    int gmb = m0 + wr * 64 + fm * 16 + g * 4;
#pragma unroll
    for (int fn = 0; fn < 4; ++fn) {
      int gn = n0 + wc * 64 + fn * 16 + l15;
      if (gn >= Nreal) continue;
#pragma unroll
      for (int j = 0; j < 4; ++j) {
        int gm = gmb + j;
        if (gm < M) C[(size_t)gm * ldc + gn] = (_Float16)acc[fm][fn][j];
      }
    }
  }
}

// ---------------- MFMA fp16 split-K GEMM: P[z][M][N] += A @ Bt^T over K-chunk z ----------------
__global__ __launch_bounds__(256) void mfma_splitk_kernel(
    const _Float16* __restrict__ A, const _Float16* __restrict__ Bt,
    float* __restrict__ P, int M, int Kpad, int N, int ktpc) {
  __shared__ __align__(16) char smem[32768];
  char* AsB = smem;
  char* BsB = smem + 16384;
  int tid = threadIdx.x;
  int lane = tid & 63, wid = tid >> 6;
  int l15 = lane & 15, g = lane >> 4;
  int wr = wid >> 1, wc = wid & 1;
  int m0 = blockIdx.y * 128, n0 = blockIdx.x * 128;
  int z = blockIdx.z;
  int KT = Kpad >> 6;
  int ktb = z * ktpc;
  int kte = min(KT, ktb + ktpc);
  f32x4 acc[4][4];
#pragma unroll
  for (int i = 0; i < 4; ++i)
#pragma unroll
    for (int j = 0; j < 4; ++j) acc[i][j] = (f32x4){0.f, 0.f, 0.f, 0.f};

  half8_t pa[4], pb[4];
  {
    int k0 = ktb << 6;
#pragma unroll
    for (int i = 0; i < 4; ++i) {
      int r = i * 32 + (tid >> 3);
      int cs = (tid & 7) ^ (r & 7);
      int ga = min(m0 + r, M - 1);
      pa[i] = *(const half8_t*)(A + (size_t)ga * Kpad + k0 + cs * 8);
      pb[i] = *(const half8_t*)(Bt + (size_t)(n0 + r) * Kpad + k0 + cs * 8);
    }
  }
  for (int kt = ktb; kt < kte; ++kt) {
    __syncthreads();
#pragma unroll
    for (int i = 0; i < 4; ++i) {
      *(half8_t*)(AsB + i * 4096 + tid * 16) = pa[i];
      *(half8_t*)(BsB + i * 4096 + tid * 16) = pb[i];
    }
    __syncthreads();
    if (kt + 1 < kte) {
      int k0 = (kt + 1) << 6;
#pragma unroll
      for (int i = 0; i < 4; ++i) {
        int r = i * 32 + (tid >> 3);
        int cs = (tid & 7) ^ (r & 7);
        int ga = min(m0 + r, M - 1);
        pa[i] = *(const half8_t*)(A + (size_t)ga * Kpad + k0 + cs * 8);
        pb[i] = *(const half8_t*)(Bt + (size_t)(n0 + r) * Kpad + k0 + cs * 8);
      }
    }
#pragma unroll
    for (int kk = 0; kk < 2; ++kk) {
      half8_t af[4], bf[4];
#pragma unroll
      for (int f = 0; f < 4; ++f) {
        int ra = wr * 64 + f * 16 + l15;
        af[f] = *(const half8_t*)(AsB + ra * 128 + (((kk * 4 + g) ^ (ra & 7)) << 4));
        int cb = wc * 64 + f * 16 + l15;
        bf[f] = *(const half8_t*)(BsB + cb * 128 + (((kk * 4 + g) ^ (cb & 7)) << 4));
      }
#pragma unroll
      for (int fm = 0; fm < 4; ++fm)
#pragma unroll
        for (int fn = 0; fn < 4; ++fn)
          acc[fm][fn] = __builtin_amdgcn_mfma_f32_16x16x32_f16(af[fm], bf[fn], acc[fm][fn], 0, 0, 0);
    }
  }
  size_t zb = (size_t)z * M;
#pragma unroll
  for (int fm = 0; fm < 4; ++fm) {
    int gmb = m0 + wr * 64 + fm * 16 + g * 4;
#pragma unroll
    for (int fn = 0; fn < 4; ++fn) {
      int gn = n0 + wc * 64 + fn * 16 + l15;
      if (gn >= N) continue;
#pragma unroll
      for (int j = 0; j < 4; ++j) {
        int gm = gmb + j;
        if (gm < M) P[(zb + gm) * N + gn] = acc[fm][fn][j];
      }
    }
  }
}

// ---------------- split-K reduce -> fp16 (+bias, opt relu); skips cols >= N ----------------
__global__ void reduce16_kernel(const float* __restrict__ P, const float* __restrict__ bias,
                                _Float16* __restrict__ O, int M, int N, int ldo,
                                int S, int relu) {
  int idx = blockIdx.x * blockDim.x + threadIdx.x;
  if (idx >= M * ldo) return;
  int row = idx / ldo, col = idx - row * ldo;
  if (col >= N) return;
  float s = bias[col];
  int MN = M * N;
  for (int z = 0; z < S; ++z) s += P[(size_t)z * MN + row * N + col];
  if (relu) s = fmaxf(s, 0.f);
  O[idx] = (_Float16)s;
}

// ---------------- FC5: [256,256](fp16) @ [256,1](fp32) wave-dot ----------------
__global__ __launch_bounds__(256) void fc5_kernel(const _Float16* __restrict__ A,
                                                  const float* __restrict__ w,
                                                  const float* __restrict__ b,
                                                  float* __restrict__ out) {
  int wid = threadIdx.x >> 6, lane = threadIdx.x & 63;
  int m = blockIdx.x * 4 + wid;
  if (m >= NB) return;
  float s = 0.f;
  for (int k = lane; k < 256; k += 64) s += (float)A[m * 256 + k] * w[k];
  s = wave_sum(s);
  if (lane == 0) out[m] = s + b[0];
}

// ---------------- attention logit dots: als/ald [N,H] (fp16 h) ----------------
__global__ __launch_bounds__(256) void al_kernel(const _Float16* __restrict__ hbuf,
                                                 const float* __restrict__ a_s,
                                                 const float* __restrict__ a_d,
                                                 float* __restrict__ als,
                                                 float* __restrict__ ald,
                                                 int H, int C, int ldh) {
  int wid = threadIdx.x >> 6, lane = threadIdx.x & 63;
  int g = blockIdx.x * 4 + wid;
  if (g >= NNODES * H) return;
  int n = g / H, h = g % H;
  const _Float16* hr = hbuf + (size_t)n * ldh + (size_t)h * C;
  float ss = 0.f, sd = 0.f;
  for (int c = lane; c < C; c += 64) {
    float v = (float)hr[c];
    ss += v * a_s[h * C + c];
    sd += v * a_d[h * C + c];
  }
  ss = wave_sum(ss);
  sd = wave_sum(sd);
  if (lane == 0) { als[g] = ss; ald[g] = sd; }
}

// ---------------- per-node segment softmax -> alpha; one gather per edge for all H ----------------
template <int H>
__global__ __launch_bounds__(256) void att_kernel_t(const float* __restrict__ als,
                                                    const float* __restrict__ ald,
                                                    const int* __restrict__ row_ptr,
                                                    const int* __restrict__ csr_src,
                                                    float* __restrict__ alpha) {
  int wid = threadIdx.x >> 6, lane = threadIdx.x & 63;
  int n = blockIdx.x * 4 + wid;
  if (n >= NNODES) return;
  int rp = row_ptr[n], deg = row_ptr[n + 1] - rp;
  float ad[H], m[H], e0[H], e1[H], ssum[H];
#pragma unroll
  for (int h = 0; h < H; ++h) { ad[h] = ald[n * H + h]; m[h] = -1e30f; ssum[h] = 0.f; }
  for (int j = lane, it = 0; j < deg; j += 64, ++it) {
    int s = csr_src[rp + j];
#pragma unroll
    for (int h = 0; h < H; ++h) {
      float e = als[s * H + h] + ad[h];
      e = (e >= 0.f) ? e : 0.2f * e;
      if (it == 0) e0[h] = e; else if (it == 1) e1[h] = e;
      m[h] = fmaxf(m[h], e);
    }
  }
#pragma unroll
  for (int h = 0; h < H; ++h) m[h] = wave_max(m[h]);
  for (int j = lane, it = 0; j < deg; j += 64, ++it) {
    int s = (it >= 2) ? csr_src[rp + j] : 0;
#pragma unroll
    for (int h = 0; h < H; ++h) {
      float e;
      if (it == 0) e = e0[h];
      else if (it == 1) e = e1[h];
      else { e = als[s * H + h] + ad[h]; e = (e >= 0.f) ? e : 0.2f * e; }
      ssum[h] += expf(e - m[h]);
    }
  }
#pragma unroll
  for (int h = 0; h < H; ++h) { ssum[h] = 1.f / (wave_sum(ssum[h]) + 1e-16f); }
  for (int j = lane, it = 0; j < deg; j += 64, ++it) {
    int s = (it >= 2) ? csr_src[rp + j] : 0;
#pragma unroll
    for (int h = 0; h < H; ++h) {
      float e;
      if (it == 0) e = e0[h];
      else if (it == 1) e = e1[h];
      else { e = als[s * H + h] + ad[h]; e = (e >= 0.f) ? e : 0.2f * e; }
      alpha[(size_t)(rp + j) * H + h] = expf(e - m[h]) * ssum[h];
    }
  }
}

// ---------------- aggregation + bias + relu -> fp16 (half8 per lane) ----------------
__global__ __launch_bounds__(256) void agg_kernel(const _Float16* __restrict__ hbuf,
                                                  const float* __restrict__ alpha,
                                                  const int* __restrict__ row_ptr,
                                                  const int* __restrict__ csr_src,
                                                  const float* __restrict__ bias,
                                                  _Float16* __restrict__ h16o,
                                                  int H, int C, int ldh, int ldo,
                                                  int HC, int nchunks) {
  int wid = threadIdx.x >> 6, lane = threadIdx.x & 63;
  int gw = blockIdx.x * 4 + wid;
  int n = gw / nchunks, chunk = gw - n * nchunks;
  if (n >= NNODES) return;
  int k0 = chunk * 512 + lane * 8;
  if (k0 >= ldo) return;
  _Float16* op = h16o + (size_t)n * ldo + k0;
  if (k0 >= HC) { *(half8_t*)op = (half8_t){}; return; }
  int h0 = k0 / C;
  int h1 = min(k0 + 7, HC - 1) / C;
  int split = (h0 + 1) * C;
  int rp = row_ptr[n], deg = row_ptr[n + 1] - rp;
  float acc[8] = {};
#pragma unroll 2
  for (int j = 0; j < deg; ++j) {
    int e = rp + j;
    int s = csr_src[e];
    float a0 = alpha[(size_t)e * H + h0];
    float a1 = alpha[(size_t)e * H + h1];
    half8_t v = *(const half8_t*)(hbuf + (size_t)s * ldh + k0);
#pragma unroll
    for (int i = 0; i < 8; ++i)
      acc[i] += ((k0 + i < split) ? a0 : a1) * (float)v[i];
  }
  half8_t o;
#pragma unroll
  for (int i = 0; i < 8; ++i)
    o[i] = (_Float16)((k0 + i < HC) ? fmaxf(acc[i] + bias[k0 + i], 0.f) : 0.f);
  *(half8_t*)op = o;
}

// ---------------- global add pool (fp16 in, fp32 out) ----------------
__global__ __launch_bounds__(256) void pool_kernel(const _Float16* __restrict__ h4,
                                                   const int* __restrict__ batch,
                                                   float* __restrict__ pooled, int F, int ldh) {
  int wid = threadIdx.x >> 6, lane = threadIdx.x & 63;
  int n = blockIdx.x * 4 + wid;
  if (n >= NNODES) return;
  int b = batch[n];
  for (int k = lane; k < F; k += 64)
    atomicAdd(&pooled[(size_t)b * F + k], (float)h4[(size_t)n * ldh + k]);
}

// ---------------- launch ----------------
extern "C" void kernel_launch(void* const* d_in, const int* in_sizes, int n_in,
                              void* d_out, int out_size, void* d_ws, size_t ws_size,
                              hipStream_t stream) {
  const float* x    = (const float*)d_in[0];
  const int*   ei   = (const int*)d_in[1];
  const int*   batch= (const int*)d_in[2];
  const float* desc = (const float*)d_in[3];
  const float* W1 = (const float*)d_in[4];  const float* as1 = (const float*)d_in[5];
  const float* ad1 = (const float*)d_in[6]; const float* b1 = (const float*)d_in[7];
  const float* W2 = (const float*)d_in[8];  const float* as2 = (const float*)d_in[9];
  const float* ad2 = (const float*)d_in[10];const float* b2 = (const float*)d_in[11];
  const float* W3 = (const float*)d_in[12]; const float* as3 = (const float*)d_in[13];
  const float* ad3 = (const float*)d_in[14];const float* b3 = (const float*)d_in[15];
  const float* W4 = (const float*)d_in[16]; const float* as4 = (const float*)d_in[17];
  const float* ad4 = (const float*)d_in[18];const float* b4 = (const float*)d_in[19];
  const float* Wg = (const float*)d_in[20]; const float* bg = (const float*)d_in[21];
  const float* Wf1 = (const float*)d_in[22];const float* bf1 = (const float*)d_in[23];
  const float* Wf2 = (const float*)d_in[24];const float* bf2 = (const float*)d_in[25];
  const float* Wf3 = (const float*)d_in[26];const float* bf3 = (const float*)d_in[27];
  const float* Wf4 = (const float*)d_in[28];const float* bf4 = (const float*)d_in[29];
  const float* Wf5 = (const float*)d_in[30];const float* bf5 = (const float*)d_in[31];
  float* out = (float*)d_out;

  // ---- workspace carve-up ----
  char* p = (char*)d_ws;
  size_t off = 0;
  auto alloc = [&](size_t bytes) -> char* {
    char* r = p + off;
    off = align256(off + bytes);
    return r;
  };
  int*      deg     = (int*)alloc(sizeof(int) * NNODES);
  int*      row_ptr = (int*)alloc(sizeof(int) * (NNODES + 1));
  int*      cursor  = (int*)alloc(sizeof(int) * NNODES);
  int*      csr_src = (int*)alloc(sizeof(int) * ETOT);
  float*    als     = (float*)alloc(sizeof(float) * NNODES * 5);
  float*    ald     = (float*)alloc(sizeof(float) * NNODES * 5);
  float*    alpha   = (float*)alloc(sizeof(float) * (size_t)ETOT * 5);
  _Float16* x16     = (_Float16*)alloc(sizeof(_Float16) * (size_t)NNODES * 64);
  _Float16* hA16    = (_Float16*)alloc(sizeof(_Float16) * ((size_t)NNODES * 856 + 1024));  // node GEMM out; head split-K partials later
  _Float16* h16     = (_Float16*)alloc(sizeof(_Float16) * ((size_t)NNODES * 896 + 1024));  // agg out / next GEMM in
  _Float16* Wt      = (_Float16*)alloc(sizeof(_Float16) * 1024 * 2304);                    // max head weight (FC1)
  float*    pooled  = (float*)alloc(sizeof(float) * NB * 570);
  _Float16* p16     = (_Float16*)alloc(sizeof(_Float16) * NB * 576);
  _Float16* z16     = (_Float16*)alloc(sizeof(_Float16) * NB * 2304);
  _Float16* t16     = (_Float16*)alloc(sizeof(_Float16) * NB * 2048);
  _Float16* u16     = (_Float16*)alloc(sizeof(_Float16) * NB * 2048);
  _Float16* v16     = (_Float16*)alloc(sizeof(_Float16) * NB * 256);
  (void)ws_size;

  // ---- CSR build ----
  hipMemsetAsync(deg, 0, sizeof(int) * NNODES, stream);
  {
    dim3 g((ETOT + 255) / 256);
    count_kernel<<<g, 256, 0, stream>>>(ei, deg);
    scan_kernel<<<1, 1024, 0, stream>>>(deg, row_ptr, cursor);
    scatter_kernel<<<g, 256, 0, stream>>>(ei, cursor, csr_src);
  }
  convert_x_kernel<<<(NNODES * 64 + 255) / 256, 256, 0, stream>>>(x, x16);

  dim3 gnode((NNODES + 3) / 4);

  // ---- GAT layers (fp16 MFMA node GEMMs) ----
  struct LayerDef { const float* W; const float* a_s; const float* a_d; const float* b;
                    int K; int H; int C; int Kpad; int Npad; int ldh; int ldo; };
  LayerDef L[4] = {
    { W1, as1, ad1, b1, INDIM, 5, 114,  64, 640, 572, 576 },
    { W2, as2, ad2, b2, 570,   5, 171, 576, 896, 856, 896 },
    { W3, as3, ad3, b3, 855,   5, 114, 896, 640, 572, 576 },
    { W4, as4, ad4, b4, 570,   1, 570, 576, 640, 572, 576 },
  };
  for (int l = 0; l < 4; ++l) {
    int HC = L[l].H * L[l].C;
    {
      int tot = L[l].Npad * L[l].Kpad;
      convert_wt_kernel<<<(tot + 255) / 256, 256, 0, stream>>>(L[l].W, Wt, L[l].K, HC,
                                                               L[l].Kpad, L[l].Npad);
    }
    {
      const _Float16* Ain = (l == 0) ? x16 : h16;
      dim3 g(L[l].Npad / 128, (NNODES + 127) / 128);
      mfma_gemm_kernel<<<g, 256, 0, stream>>>(Ain, Wt, hA16, NNODES, L[l].Kpad, HC, L[l].ldh);
    }
    {
      dim3 g((NNODES * L[l].H + 3) / 4);
      al_kernel<<<g, 256, 0, stream>>>(hA16, L[l].a_s, L[l].a_d, als, ald, L[l].H, L[l].C, L[l].ldh);
    }
    if (L[l].H == 5)
      att_kernel_t<5><<<gnode, 256, 0, stream>>>(als, ald, row_ptr, csr_src, alpha);
    else
      att_kernel_t<1><<<gnode, 256, 0, stream>>>(als, ald, row_ptr, csr_src, alpha);
    {
      int nchunks = (L[l].ldo + 511) / 512;
      dim3 g((NNODES * nchunks + 3) / 4);
      agg_kernel<<<g, 256, 0, stream>>>(hA16, alpha, row_ptr, csr_src, L[l].b, h16,
                                        L[l].H, L[l].C, L[l].ldh, L[l].ldo, HC, nchunks);
    }
  }

  // ---- pooling (layer-4 h16, stride 576, 570 cols) ----
  hipMemsetAsync(pooled, 0, sizeof(float) * NB * 570, stream);
  pool_kernel<<<gnode, 256, 0, stream>>>(h16, batch, pooled, 570, 576);

  // ---- head MLP: fp16 MFMA split-K (partials in hA16 region, 16.8MB <= 17.1MB) ----
  float* partials = (float*)hA16;
  auto head_gemm = [&](const _Float16* A, const float* W, const float* bias,
                       _Float16* O, int K, int Kpad, int N, int ldo, int relu,
                       int ktpc, int S) {
    int tot = N * Kpad;
    convert_wt_kernel<<<(tot + 255) / 256, 256, 0, stream>>>(W, Wt, K, N, Kpad, N);
    dim3 g(N / 128, NB / 128, S);
    mfma_splitk_kernel<<<g, 256, 0, stream>>>(A, Wt, partials, NB, Kpad, N, ktpc);
    int totO = NB * ldo;
    reduce16_kernel<<<(totO + 255) / 256, 256, 0, stream>>>(partials, bias, O, NB, N, ldo, S, relu);
  };

  pooled16_kernel<<<(NB * 576 + 255) / 256, 256, 0, stream>>>(pooled, p16);
  // g = pooled @ Wg + bg  -> z16[:, 0:1024]
  head_gemm(p16, Wg, bg, z16, 570, 576, 1024, 2304, 0, 3, 3);
  desc_fill_kernel<<<(NB * 1280 + 255) / 256, 256, 0, stream>>>(desc, z16);
  // FC1: z16 [256,2304] -> t16 [256,1024]
  head_gemm(z16, Wf1, bf1, t16, 1024 + DESCD, 2304, 1024, 1024, 1, 3, 12);
  // FC2: t16 -> u16 [256,2048]
  head_gemm(t16, Wf2, bf2, u16, 1024, 1024, 2048, 2048, 1, 2, 8);
  // FC3: u16 -> t16 [256,1024]
  head_gemm(u16, Wf3, bf3, t16, 2048, 2048, 1024, 1024, 1, 2, 16);
  // FC4: t16 -> v16 [256,256]
  head_gemm(t16, Wf4, bf4, v16, 1024, 1024, 256, 256, 1, 1, 16);
  // FC5
  fc5_kernel<<<(NB + 3) / 4, 256, 0, stream>>>(v16, Wf5, bf5, out);
}